// Round 6
// baseline (1727.422 us; speedup 1.0000x reference)
//
#include <hip/hip_runtime.h>
#include <stdint.h>

#define DIM_    1024
#define INTER_  512

typedef short bf16x4 __attribute__((ext_vector_type(4)));
typedef short bf16x8 __attribute__((ext_vector_type(8)));
typedef float f32x4  __attribute__((ext_vector_type(4)));

__device__ __forceinline__ unsigned short f2bf(float f) {
  union { float f; unsigned u; } v; v.f = f;
  return (unsigned short)((v.u + 0x7FFFu + ((v.u >> 16) & 1u)) >> 16);
}
__device__ __forceinline__ unsigned f2bf2(float a, float b) {
  union { float f; unsigned u; } va, vb; va.f = a; vb.f = b;
  unsigned ra = (va.u + 0x7FFFu + ((va.u >> 16) & 1u)) >> 16;
  unsigned rb = (vb.u + 0x7FFFu + ((vb.u >> 16) & 1u)) >> 16;
  return ra | (rb << 16);
}
__device__ __forceinline__ float bfhi(unsigned u) {
  union { unsigned u; float f; } v; v.u = u & 0xffff0000u; return v.f;
}
__device__ __forceinline__ float bflo(unsigned u) {
  union { unsigned u; float f; } v; v.u = u << 16; return v.f;
}

__device__ __forceinline__ void gl16(const void* g, void* l) {
  __builtin_amdgcn_global_load_lds(
      (const __attribute__((address_space(1))) unsigned int*)g,
      (__attribute__((address_space(3))) unsigned int*)l, 16, 0, 0);
}

// ---------------------------------------------------------------- gate ----
__global__ __launch_bounds__(256) void gate_kernel(
    const float* __restrict__ x, const float* __restrict__ gw,
    const float* __restrict__ gb, int* __restrict__ idx, float* __restrict__ wts,
    unsigned short* __restrict__ xb) {
  __shared__ double s_sc[4][32];
  __shared__ double s_gs[4][8];
  const int wid = threadIdx.x >> 6, lane = threadIdx.x & 63;
  const int t = blockIdx.x * 4 + wid;
  {
    const float* xrow = x + (size_t)t * DIM_ + lane * 16;
    unsigned short* xbrow = xb + (size_t)t * DIM_ + lane * 16;
    float4 f0 = *(const float4*)(xrow);
    float4 f1 = *(const float4*)(xrow + 4);
    float4 f2v = *(const float4*)(xrow + 8);
    float4 f3v = *(const float4*)(xrow + 12);
    uint4 o0, o1;
    o0.x = f2bf2(f0.x, f0.y);  o0.y = f2bf2(f0.z, f0.w);
    o0.z = f2bf2(f1.x, f1.y);  o0.w = f2bf2(f1.z, f1.w);
    o1.x = f2bf2(f2v.x, f2v.y); o1.y = f2bf2(f2v.z, f2v.w);
    o1.z = f2bf2(f3v.x, f3v.y); o1.w = f2bf2(f3v.z, f3v.w);
    *(uint4*)(xbrow) = o0;
    *(uint4*)(xbrow + 8) = o1;
  }
  const int e = lane & 31, half = lane >> 5;
  const float* xr  = x  + (size_t)t * DIM_ + half * 512;
  const float* gwp = gw + (size_t)half * 512 * 32 + e;
  double a0 = 0, a1 = 0, a2 = 0, a3 = 0;
  for (int k = 0; k < 512; k += 4) {
    float4 xv = *(const float4*)(xr + k);
    a0 += (double)xv.x * (double)gwp[(k + 0) * 32];
    a1 += (double)xv.y * (double)gwp[(k + 1) * 32];
    a2 += (double)xv.z * (double)gwp[(k + 2) * 32];
    a3 += (double)xv.w * (double)gwp[(k + 3) * 32];
  }
  double lg = (a0 + a1) + (a2 + a3);
  lg += __shfl_xor(lg, 32);
  lg += (double)gb[e];
  double m = lg;
  #pragma unroll
  for (int d = 1; d < 32; d <<= 1) m = fmax(m, __shfl_xor(m, d));
  double ex = exp(lg - m);
  double ssum = ex;
  #pragma unroll
  for (int d = 1; d < 32; d <<= 1) ssum += __shfl_xor(ssum, d);
  double sc = ex / ssum;
  double p  = __shfl_xor(sc, 1);
  double m1 = fmax(sc, p), n1 = fmin(sc, p);
  double m2 = __shfl_xor(m1, 2), n2 = __shfl_xor(n1, 2);
  double gs = (m1 >= m2) ? (m1 + fmax(n1, m2)) : (m2 + fmax(n2, m1));
  if (lane < 32) {
    s_sc[wid][e] = sc;
    if ((e & 3) == 0) s_gs[wid][e >> 2] = gs;
  }
  __syncthreads();
  if (lane == 0) {
    unsigned kmask = 0;
    for (int it = 0; it < 4; ++it) {
      int bg = 0; double bv = -1.0;
      for (int g = 0; g < 8; ++g)
        if (!((kmask >> g) & 1u) && s_gs[wid][g] > bv) { bv = s_gs[wid][g]; bg = g; }
      kmask |= 1u << bg;
    }
    unsigned umask = 0;
    for (int slot = 0; slot < 4; ++slot) {
      int be = 0; double bv = -1.0;
      for (int ee = 0; ee < 32; ++ee)
        if (((kmask >> (ee >> 2)) & 1u) && !((umask >> ee) & 1u) && s_sc[wid][ee] > bv) {
          bv = s_sc[wid][ee]; be = ee;
        }
      umask |= 1u << be;
      idx[t * 4 + slot] = be;
      wts[t * 4 + slot] = (float)bv;
    }
  }
}

// ------------------------------------------------- dispatch bookkeeping ----
__global__ __launch_bounds__(256) void count_kernel(const int* __restrict__ idx,
                                                    int* __restrict__ meta) {
  __shared__ int h[32];
  int tid = threadIdx.x;
  if (tid < 32) h[tid] = 0;
  __syncthreads();
  atomicAdd(&h[idx[blockIdx.x * 256 + tid]], 1);
  __syncthreads();
  if (tid < 32 && h[tid]) atomicAdd(&meta[tid], h[tid]);
}

__global__ void scan_kernel(int* __restrict__ meta) {
  int lane = threadIdx.x & 63;
  if (lane < 32) {
    int c = meta[lane];
    int pre = c;
    #pragma unroll
    for (int d = 1; d < 32; d <<= 1) { int t = __shfl_up(pre, d); if (lane >= d) pre += t; }
    int excl = pre - c;
    meta[64 + lane] = excl;
    meta[32 + lane] = excl;
    int nt = (c + 127) >> 7;
    int ntp = nt;
    #pragma unroll
    for (int d = 1; d < 32; d <<= 1) { int t = __shfl_up(ntp, d); if (lane >= d) ntp += t; }
    int ntExcl = ntp - nt;
    for (int k = 0; k < nt; ++k) { meta[128 + ntExcl + k] = lane; meta[1184 + ntExcl + k] = k << 7; }
    if (lane == 31) { meta[96] = excl + c; meta[97] = ntExcl + nt; }
  }
}

__global__ __launch_bounds__(256) void scatter_kernel(
    const int* __restrict__ idx, int* __restrict__ meta,
    int* __restrict__ tok, int* __restrict__ inv) {
  int i = blockIdx.x * 256 + threadIdx.x;
  int lane = threadIdx.x & 63;
  int e = idx[i];
  unsigned long long m = ~0ull;
  #pragma unroll
  for (int b = 0; b < 5; ++b) {
    unsigned long long vote = __ballot((e >> b) & 1);
    m &= ((e >> b) & 1) ? vote : ~vote;
  }
  int leader = __ffsll((long long)m) - 1;
  int rank = __popcll(m & ((1ull << lane) - 1));
  int base = 0;
  if (lane == leader) base = atomicAdd(&meta[32 + e], (int)__popcll(m));
  base = __shfl(base, leader);
  int p = base + rank;
  tok[p] = i >> 2;
  inv[i] = p;
}

// ----------------------------------------------------------- repacking ----
// plain: weight [e][K][N] fp32 -> bf16 4KB tiles (col j at j*64, 16B slot q
// holds k-octet q^sz(j), sz(j)=(j&3)^((j>>2)&3)).
__global__ __launch_bounds__(256) void repack_kernel(
    const float* __restrict__ src, unsigned short* __restrict__ dst,
    int K, int N, int tilesPerMat) {
  const int w = blockIdx.x * 4 + (threadIdx.x >> 6);
  const int j = threadIdx.x & 63;
  const int e = w / tilesPerMat, rem = w % tilesPerMat;
  const int kSteps = K >> 5;
  const int nt = rem / kSteps, kq = rem % kSteps;
  const float* s = src + (size_t)e * K * N + (size_t)(kq * 32) * N + nt * 64 + j;
  float v[32];
  #pragma unroll
  for (int kk = 0; kk < 32; ++kk) v[kk] = s[(size_t)kk * N];
  char* d = (char*)dst + (size_t)w * 4096 + j * 64;
  const int sz = (j & 3) ^ ((j >> 2) & 3);
  #pragma unroll
  for (int q = 0; q < 4; ++q) {
    int o = (q ^ sz) * 8;
    uint4 tv;
    tv.x = f2bf2(v[o + 0], v[o + 1]);
    tv.y = f2bf2(v[o + 2], v[o + 3]);
    tv.z = f2bf2(v[o + 4], v[o + 5]);
    tv.w = f2bf2(v[o + 6], v[o + 7]);
    *(uint4*)(d + q * 16) = tv;
  }
}

// interleaved: w1/w3 columns merged, 16-col blocks alternating (j_g>>4)&1.
__global__ __launch_bounds__(256) void repack13_kernel(
    const float* __restrict__ src1, const float* __restrict__ src3,
    unsigned short* __restrict__ dst, int K, int N, int jtTiles) {
  const int w = blockIdx.x * 4 + (threadIdx.x >> 6);
  const int j = threadIdx.x & 63;
  const int kSteps = K >> 5;
  const int tpm = jtTiles * kSteps;
  const int e = w / tpm, rem = w % tpm;
  const int jt = rem / kSteps, kq = rem % kSteps;
  const int jg = jt * 64 + j;
  const int c = ((jg >> 5) << 4) + (jg & 15);
  const float* s = (((jg >> 4) & 1) ? src3 : src1)
                 + (size_t)e * K * N + (size_t)(kq * 32) * N + c;
  float v[32];
  #pragma unroll
  for (int kk = 0; kk < 32; ++kk) v[kk] = s[(size_t)kk * N];
  char* d = (char*)dst + (size_t)w * 4096 + j * 64;
  const int sz = (j & 3) ^ ((j >> 2) & 3);
  #pragma unroll
  for (int q = 0; q < 4; ++q) {
    int o = (q ^ sz) * 8;
    uint4 tv;
    tv.x = f2bf2(v[o + 0], v[o + 1]);
    tv.y = f2bf2(v[o + 2], v[o + 3]);
    tv.z = f2bf2(v[o + 4], v[o + 5]);
    tv.w = f2bf2(v[o + 6], v[o + 7]);
    *(uint4*)(d + q * 16) = tv;
  }
}

// ============ m97-shape GEMM core, 2-phase double-buffered (BK=64) =========
// Per 32KB buffer: A [kk][128 rows][64B] at 0; B [kk][2 tiles][64 cols][64B]
// at 16384. Loop unrolled x2 so buffer bases are compile-time constants:
//   STAGE(b1,ks+1); COMPUTE(b0); sync; STAGE(b0,ks+2); COMPUTE(b1); sync;
// -> 1 barrier per K-step, staged loads drain after a full compute phase.

#define GEMM_PRE()                                                            \
  const int tid = threadIdx.x, lane = tid & 63, wave = tid >> 6;              \
  const int wm = wave >> 1, wn = wave & 1;                                    \
  const int f = lane & 15, g = lane >> 4;                                     \
  const int rr = ((tid >> 6) << 4) + ((tid & 63) >> 2);                       \
  const int sl = tid & 3;                                                     \
  const int soff = ((sl ^ ((rr & 3) ^ ((rr >> 2) & 1))) << 4);                \
  const int vfr = (f & 3) ^ ((f >> 2) & 1);                                   \
  const int aro = (wm * 64 + f) * 64 + ((g ^ vfr) << 4);                      \
  int bofs[4];                                                                \
  _Pragma("unroll")                                                           \
  for (int ni = 0; ni < 4; ++ni) {                                            \
    int j = wn * 64 + ni * 16 + f;                                            \
    int jl = j & 63;                                                          \
    int szv = (jl & 3) ^ ((jl >> 2) & 3);                                     \
    bofs[ni] = 16384 + (j >> 6) * 4096 + jl * 64 + ((g ^ szv) << 4);          \
  }                                                                           \
  f32x4 acc[4][4];                                                            \
  const f32x4 zz = {0.f, 0.f, 0.f, 0.f};                                      \
  _Pragma("unroll")                                                           \
  for (int mi = 0; mi < 4; ++mi)                                              \
    _Pragma("unroll")                                                         \
    for (int ni = 0; ni < 4; ++ni) acc[mi][ni] = zz;

#define GEMM_STAGE(B, ks)                                                     \
  gl16(pA0 + (ks) * 128,        lds + (B) + wave * 1024);                     \
  gl16(pA1 + (ks) * 128,        lds + (B) + 4096 + wave * 1024);              \
  gl16(pA0 + (ks) * 128 + 64,   lds + (B) + 8192 + wave * 1024);              \
  gl16(pA1 + (ks) * 128 + 64,   lds + (B) + 12288 + wave * 1024);             \
  gl16(bimg0 + (size_t)(ks) * 8192,        lds + (B) + 16384 + wave * 1024);  \
  gl16(bimg1 + (size_t)(ks) * 8192,        lds + (B) + 20480 + wave * 1024);  \
  gl16(bimg0 + (size_t)(ks) * 8192 + 4096, lds + (B) + 24576 + wave * 1024);  \
  gl16(bimg1 + (size_t)(ks) * 8192 + 4096, lds + (B) + 28672 + wave * 1024);

#define GEMM_COMPUTE(B)                                                       \
  _Pragma("unroll")                                                           \
  for (int kk = 0; kk < 2; ++kk) {                                            \
    bf16x8 af[4], bfv[4];                                                     \
    _Pragma("unroll")                                                         \
    for (int mi = 0; mi < 4; ++mi)                                            \
      af[mi] = *(const bf16x8*)(lds + (B) + kk * 8192 + aro + mi * 1024);     \
    _Pragma("unroll")                                                         \
    for (int ni = 0; ni < 4; ++ni)                                            \
      bfv[ni] = *(const bf16x8*)(lds + (B) + kk * 8192 + bofs[ni]);           \
    _Pragma("unroll")                                                         \
    for (int ni = 0; ni < 4; ++ni)                                            \
      _Pragma("unroll")                                                       \
      for (int mi = 0; mi < 4; ++mi)                                          \
        acc[mi][ni] = __builtin_amdgcn_mfma_f32_16x16x32_bf16(                \
            af[mi], bfv[ni], acc[mi][ni], 0, 0, 0);                           \
  }

#define GEMM_LOOP(NK)                                                         \
  GEMM_STAGE(0, 0);                                                           \
  __syncthreads();                                                            \
  for (int ks = 0; ks < (NK); ks += 2) {                                      \
    GEMM_STAGE(32768, ks + 1);                                                \
    GEMM_COMPUTE(0);                                                          \
    __syncthreads();                                                          \
    if (ks + 2 < (NK)) GEMM_STAGE(0, ks + 2);                                 \
    GEMM_COMPUTE(32768);                                                      \
    __syncthreads();                                                          \
  }

// --------------------------------------------------------- shared GEMM1 ----
__global__ __launch_bounds__(256) void s1_kernel(
    const unsigned short* __restrict__ xb, const unsigned short* __restrict__ w13,
    const float* __restrict__ sb1, const float* __restrict__ sb3,
    unsigned short* __restrict__ Hs) {
  __shared__ char lds[65536];
  const int m0 = blockIdx.y * 128;
  GEMM_PRE();
  const char* pA0 = (const char*)xb + (size_t)(m0 + rr) * 2048 + soff;
  const char* pA1 = (const char*)xb + (size_t)(m0 + rr + 64) * 2048 + soff;
  const char* bimg0 = (const char*)w13 + (size_t)((blockIdx.x * 2 + 0) * 32) * 4096 + tid * 16;
  const char* bimg1 = (const char*)w13 + (size_t)((blockIdx.x * 2 + 1) * 32) * 4096 + tid * 16;
  GEMM_LOOP(16);
  const int bx64 = blockIdx.x * 64;
  #pragma unroll
  for (int p = 0; p < 2; ++p) {
    int col = bx64 + (wn * 2 + p) * 16 + f;
    float bb1 = sb1[col], bb3 = sb3[col];
    #pragma unroll
    for (int mi = 0; mi < 4; ++mi) {
      int rb = wm * 64 + mi * 16 + (g << 2);
      #pragma unroll
      for (int r = 0; r < 4; ++r) {
        float v1 = acc[mi][2 * p][r] + bb1;
        float v3 = acc[mi][2 * p + 1][r] + bb3;
        float h = (v1 / (1.f + __expf(-v1))) * v3;
        Hs[(size_t)(m0 + rb + r) * 1024 + col] = f2bf(h);
      }
    }
  }
}

// --------------------------------------------------------- shared GEMM2 ----
__global__ __launch_bounds__(256) void s2_kernel(
    const unsigned short* __restrict__ Hs, const unsigned short* __restrict__ b2i,
    const float* __restrict__ sb2, float* __restrict__ out) {
  __shared__ char lds[65536];
  const int m0 = blockIdx.y * 128;
  const int n0 = blockIdx.x * 128;
  GEMM_PRE();
  const char* pA0 = (const char*)Hs + (size_t)(m0 + rr) * 2048 + soff;
  const char* pA1 = (const char*)Hs + (size_t)(m0 + rr + 64) * 2048 + soff;
  const char* bimg0 = (const char*)b2i + (size_t)((blockIdx.x * 2 + 0) * 32) * 4096 + tid * 16;
  const char* bimg1 = (const char*)b2i + (size_t)((blockIdx.x * 2 + 1) * 32) * 4096 + tid * 16;
  GEMM_LOOP(16);
  #pragma unroll
  for (int ni = 0; ni < 4; ++ni) {
    int col = n0 + wn * 64 + ni * 16 + f;
    float bb = sb2[col];
    #pragma unroll
    for (int mi = 0; mi < 4; ++mi) {
      int rb = m0 + wm * 64 + mi * 16 + (g << 2);
      #pragma unroll
      for (int r = 0; r < 4; ++r)
        out[(size_t)(rb + r) * 1024 + col] = acc[mi][ni][r] + bb;
    }
  }
}

// --------------------------------------------------------- routed GEMM1 ----
__global__ __launch_bounds__(256) void g1_kernel(
    const unsigned short* __restrict__ xb, const unsigned short* __restrict__ w13,
    const float* __restrict__ b1, const float* __restrict__ b3,
    const int* __restrict__ tok, const int* __restrict__ meta,
    unsigned short* __restrict__ H) {
  __shared__ char lds[65536];
  if ((int)blockIdx.y >= meta[97]) return;
  const int e = meta[128 + blockIdx.y], m0 = meta[1184 + blockIdx.y];
  const int off_e = meta[64 + e], nrem = meta[e] - m0;
  GEMM_PRE();
  int tr0 = tok[off_e + m0 + ((rr < nrem) ? rr : 0)];
  int tr1 = tok[off_e + m0 + ((rr + 64 < nrem) ? rr + 64 : 0)];
  const char* pA0 = (const char*)xb + (size_t)tr0 * 2048 + soff;
  const char* pA1 = (const char*)xb + (size_t)tr1 * 2048 + soff;
  const char* bimg0 = (const char*)w13 + (size_t)((e * 16 + blockIdx.x * 2 + 0) * 32) * 4096 + tid * 16;
  const char* bimg1 = (const char*)w13 + (size_t)((e * 16 + blockIdx.x * 2 + 1) * 32) * 4096 + tid * 16;
  GEMM_LOOP(16);
  const int bx64 = blockIdx.x * 64;
  #pragma unroll
  for (int p = 0; p < 2; ++p) {
    int col = bx64 + (wn * 2 + p) * 16 + f;
    float bb1 = b1[e * 512 + col], bb3 = b3[e * 512 + col];
    #pragma unroll
    for (int mi = 0; mi < 4; ++mi) {
      int rb = wm * 64 + mi * 16 + (g << 2);
      #pragma unroll
      for (int r = 0; r < 4; ++r) {
        int row = rb + r;
        if (row < nrem) {
          float v1 = acc[mi][2 * p][r] + bb1;
          float v3 = acc[mi][2 * p + 1][r] + bb3;
          float h = (v1 / (1.f + __expf(-v1))) * v3;
          H[(size_t)(off_e + m0 + row) * 512 + col] = f2bf(h);
        }
      }
    }
  }
}

// --------------------------------------------------------- routed GEMM2 ----
__global__ __launch_bounds__(256) void g2_kernel(
    const unsigned short* __restrict__ H, const unsigned short* __restrict__ w2i,
    const float* __restrict__ b2, const int* __restrict__ meta,
    unsigned short* __restrict__ Y, int cbase) {
  __shared__ char lds[65536];
  if ((int)blockIdx.y >= meta[97]) return;
  const int e = meta[128 + blockIdx.y], m0 = meta[1184 + blockIdx.y];
  const int off_e = meta[64 + e], nrem = meta[e] - m0;
  const int n0 = cbase + blockIdx.x * 128;
  GEMM_PRE();
  const char* pA0 = (const char*)H + (size_t)(off_e + m0 + ((rr < nrem) ? rr : 0)) * 1024 + soff;
  const char* pA1 = (const char*)H + (size_t)(off_e + m0 + ((rr + 64 < nrem) ? rr + 64 : 0)) * 1024 + soff;
  const int ntb = (n0 >> 6);
  const char* bimg0 = (const char*)w2i + (size_t)((e * 16 + ntb + 0) * 16) * 4096 + tid * 16;
  const char* bimg1 = (const char*)w2i + (size_t)((e * 16 + ntb + 1) * 16) * 4096 + tid * 16;
  GEMM_LOOP(8);
  #pragma unroll
  for (int ni = 0; ni < 4; ++ni) {
    int col = n0 + wn * 64 + ni * 16 + f;
    float bb = b2[e * 1024 + col];
    int ycol = col - cbase;
    #pragma unroll
    for (int mi = 0; mi < 4; ++mi) {
      int rb = wm * 64 + mi * 16 + (g << 2);
      #pragma unroll
      for (int r = 0; r < 4; ++r) {
        int row = rb + r;
        if (row < nrem)
          Y[(size_t)(off_e + m0 + row) * 512 + ycol] = f2bf(acc[mi][ni][r] + bb);
      }
    }
  }
}

// ------------------------------------------------------------- combine ----
__global__ __launch_bounds__(256) void combine_kernel(
    const unsigned short* __restrict__ Y, const int* __restrict__ inv,
    const float* __restrict__ wts, float* __restrict__ out, int cbase) {
  int t = blockIdx.x * 2 + (threadIdx.x >> 7);
  int c = (threadIdx.x & 127) * 4;
  int4 iv = *(const int4*)(inv + t * 4);
  float4 wv = *(const float4*)(wts + t * 4);
  float* op = out + (size_t)t * 1024 + cbase + c;
  float4 o = *(float4*)op;
  uint2 u;
  u = *(const uint2*)(Y + (size_t)iv.x * 512 + c);
  o.x += wv.x * bflo(u.x); o.y += wv.x * bfhi(u.x);
  o.z += wv.x * bflo(u.y); o.w += wv.x * bfhi(u.y);
  u = *(const uint2*)(Y + (size_t)iv.y * 512 + c);
  o.x += wv.y * bflo(u.x); o.y += wv.y * bfhi(u.x);
  o.z += wv.y * bflo(u.y); o.w += wv.y * bfhi(u.y);
  u = *(const uint2*)(Y + (size_t)iv.z * 512 + c);
  o.x += wv.z * bflo(u.x); o.y += wv.z * bfhi(u.x);
  o.z += wv.z * bflo(u.y); o.w += wv.z * bfhi(u.y);
  u = *(const uint2*)(Y + (size_t)iv.w * 512 + c);
  o.x += wv.w * bflo(u.x); o.y += wv.w * bfhi(u.x);
  o.z += wv.w * bflo(u.y); o.w += wv.w * bfhi(u.y);
  *(float4*)op = o;
}

// ------------------------------------------------------------------ host ----
extern "C" void kernel_launch(void* const* d_in, const int* in_sizes, int n_in,
                              void* d_out, int out_size, void* d_ws, size_t ws_size,
                              hipStream_t stream) {
  const float* x   = (const float*)d_in[0];
  const float* gw  = (const float*)d_in[1];
  const float* gb  = (const float*)d_in[2];
  const float* w1  = (const float*)d_in[3];
  const float* b1  = (const float*)d_in[4];
  const float* w3  = (const float*)d_in[5];
  const float* b3  = (const float*)d_in[6];
  const float* w2  = (const float*)d_in[7];
  const float* b2  = (const float*)d_in[8];
  const float* sw1 = (const float*)d_in[9];
  const float* sb1 = (const float*)d_in[10];
  const float* sw3 = (const float*)d_in[11];
  const float* sb3 = (const float*)d_in[12];
  const float* sw2 = (const float*)d_in[13];
  const float* sb2 = (const float*)d_in[14];
  float* out = (float*)d_out;
  char* ws = (char*)d_ws;

  // [0,134M): H (g1 out; s1's Hs aliases low 67M)
  // [134M,268M): xb(64MiB)+W13I(64MiB) -- dead after g1, reused as Y(128MiB)
  const size_t OFF_XB   = 134217728;
  const size_t OFF_W13I = 201326592;            // 64 MiB
  const size_t OFF_W2I  = 268435456;            // 32 MiB
  const size_t OFF_S13I = 301989888;            // 4 MiB
  const size_t OFF_SW2I = 306184192;            // 2 MiB
  const size_t OFF_IDX  = 308281344;
  const size_t OFF_WTS  = 308805632;
  const size_t OFF_TOK  = 309329920;
  const size_t OFF_INV  = 309854208;
  const size_t OFF_META = 310378496;
  if (ws_size < OFF_META + 8960) return;

  unsigned short* H    = (unsigned short*)ws;
  unsigned short* xb   = (unsigned short*)(ws + OFF_XB);
  unsigned short* Yb   = (unsigned short*)(ws + OFF_XB);   // aliases xb+w13i
  unsigned short* w13i = (unsigned short*)(ws + OFF_W13I);
  unsigned short* w2i  = (unsigned short*)(ws + OFF_W2I);
  unsigned short* s13i = (unsigned short*)(ws + OFF_S13I);
  unsigned short* sw2i = (unsigned short*)(ws + OFF_SW2I);
  int*   idx  = (int*)(ws + OFF_IDX);
  float* wts  = (float*)(ws + OFF_WTS);
  int*   tokl = (int*)(ws + OFF_TOK);
  int*   inv  = (int*)(ws + OFF_INV);
  int*   meta = (int*)(ws + OFF_META);

  hipMemsetAsync(meta, 0, 128, stream);
  gate_kernel<<<dim3(8192), dim3(256), 0, stream>>>(x, gw, gb, idx, wts, xb);
  count_kernel<<<dim3(512), dim3(256), 0, stream>>>(idx, meta);
  scan_kernel<<<dim3(1), dim3(64), 0, stream>>>(meta);
  scatter_kernel<<<dim3(512), dim3(256), 0, stream>>>(idx, meta, tokl, inv);
  repack13_kernel<<<dim3(4096), dim3(256), 0, stream>>>(w1, w3, w13i, 1024, 512, 16);
  repack_kernel<<<dim3(2048), dim3(256), 0, stream>>>(w2, w2i, 512, 1024, 256);
  repack13_kernel<<<dim3(256), dim3(256), 0, stream>>>(sw1, sw3, s13i, 1024, 1024, 32);
  repack_kernel<<<dim3(128), dim3(256), 0, stream>>>(sw2, sw2i, 1024, 1024, 512);
  s1_kernel<<<dim3(16, 256), dim3(256), 0, stream>>>(xb, s13i, sb1, sb3, H);
  s2_kernel<<<dim3(8, 256), dim3(256), 0, stream>>>(H, sw2i, sb2, out);
  g1_kernel<<<dim3(8, 1056), dim3(256), 0, stream>>>(xb, w13i, b1, b3, tokl, meta, H);
  g2_kernel<<<dim3(4, 1056), dim3(256), 0, stream>>>(H, w2i, b2, meta, Yb, 0);
  combine_kernel<<<dim3(16384), dim3(256), 0, stream>>>(Yb, inv, wts, out, 0);
  g2_kernel<<<dim3(4, 1056), dim3(256), 0, stream>>>(H, w2i, b2, meta, Yb, 512);
  combine_kernel<<<dim3(16384), dim3(256), 0, stream>>>(Yb, inv, wts, out, 512);
}

// Round 7
// 1641.400 us; speedup vs baseline: 1.0524x; 1.0524x over previous
//
#include <hip/hip_runtime.h>
#include <stdint.h>

#define DIM_    1024
#define INTER_  512

typedef short bf16x4 __attribute__((ext_vector_type(4)));
typedef short bf16x8 __attribute__((ext_vector_type(8)));
typedef float f32x4  __attribute__((ext_vector_type(4)));

__device__ __forceinline__ unsigned short f2bf(float f) {
  union { float f; unsigned u; } v; v.f = f;
  return (unsigned short)((v.u + 0x7FFFu + ((v.u >> 16) & 1u)) >> 16);
}
__device__ __forceinline__ unsigned f2bf2(float a, float b) {
  union { float f; unsigned u; } va, vb; va.f = a; vb.f = b;
  unsigned ra = (va.u + 0x7FFFu + ((va.u >> 16) & 1u)) >> 16;
  unsigned rb = (vb.u + 0x7FFFu + ((vb.u >> 16) & 1u)) >> 16;
  return ra | (rb << 16);
}
__device__ __forceinline__ float bfhi(unsigned u) {
  union { unsigned u; float f; } v; v.u = u & 0xffff0000u; return v.f;
}
__device__ __forceinline__ float bflo(unsigned u) {
  union { unsigned u; float f; } v; v.u = u << 16; return v.f;
}

__device__ __forceinline__ void gl16(const void* g, void* l) {
  __builtin_amdgcn_global_load_lds(
      (const __attribute__((address_space(1))) unsigned int*)g,
      (__attribute__((address_space(3))) unsigned int*)l, 16, 0, 0);
}

#define BARX() do { asm volatile("" ::: "memory"); \
                    __builtin_amdgcn_s_barrier();  \
                    asm volatile("" ::: "memory"); } while (0)

// ---------------------------------------------------------------- gate ----
__global__ __launch_bounds__(256) void gate_kernel(
    const float* __restrict__ x, const float* __restrict__ gw,
    const float* __restrict__ gb, int* __restrict__ idx, float* __restrict__ wts,
    unsigned short* __restrict__ xb) {
  __shared__ double s_sc[4][32];
  __shared__ double s_gs[4][8];
  const int wid = threadIdx.x >> 6, lane = threadIdx.x & 63;
  const int t = blockIdx.x * 4 + wid;
  {
    const float* xrow = x + (size_t)t * DIM_ + lane * 16;
    unsigned short* xbrow = xb + (size_t)t * DIM_ + lane * 16;
    float4 f0 = *(const float4*)(xrow);
    float4 f1 = *(const float4*)(xrow + 4);
    float4 f2v = *(const float4*)(xrow + 8);
    float4 f3v = *(const float4*)(xrow + 12);
    uint4 o0, o1;
    o0.x = f2bf2(f0.x, f0.y);  o0.y = f2bf2(f0.z, f0.w);
    o0.z = f2bf2(f1.x, f1.y);  o0.w = f2bf2(f1.z, f1.w);
    o1.x = f2bf2(f2v.x, f2v.y); o1.y = f2bf2(f2v.z, f2v.w);
    o1.z = f2bf2(f3v.x, f3v.y); o1.w = f2bf2(f3v.z, f3v.w);
    *(uint4*)(xbrow) = o0;
    *(uint4*)(xbrow + 8) = o1;
  }
  const int e = lane & 31, half = lane >> 5;
  const float* xr  = x  + (size_t)t * DIM_ + half * 512;
  const float* gwp = gw + (size_t)half * 512 * 32 + e;
  double a0 = 0, a1 = 0, a2 = 0, a3 = 0;
  for (int k = 0; k < 512; k += 4) {
    float4 xv = *(const float4*)(xr + k);
    a0 += (double)xv.x * (double)gwp[(k + 0) * 32];
    a1 += (double)xv.y * (double)gwp[(k + 1) * 32];
    a2 += (double)xv.z * (double)gwp[(k + 2) * 32];
    a3 += (double)xv.w * (double)gwp[(k + 3) * 32];
  }
  double lg = (a0 + a1) + (a2 + a3);
  lg += __shfl_xor(lg, 32);
  lg += (double)gb[e];
  double m = lg;
  #pragma unroll
  for (int d = 1; d < 32; d <<= 1) m = fmax(m, __shfl_xor(m, d));
  double ex = exp(lg - m);
  double ssum = ex;
  #pragma unroll
  for (int d = 1; d < 32; d <<= 1) ssum += __shfl_xor(ssum, d);
  double sc = ex / ssum;
  double p  = __shfl_xor(sc, 1);
  double m1 = fmax(sc, p), n1 = fmin(sc, p);
  double m2 = __shfl_xor(m1, 2), n2 = __shfl_xor(n1, 2);
  double gs = (m1 >= m2) ? (m1 + fmax(n1, m2)) : (m2 + fmax(n2, m1));
  if (lane < 32) {
    s_sc[wid][e] = sc;
    if ((e & 3) == 0) s_gs[wid][e >> 2] = gs;
  }
  __syncthreads();
  if (lane == 0) {
    unsigned kmask = 0;
    for (int it = 0; it < 4; ++it) {
      int bg = 0; double bv = -1.0;
      for (int g = 0; g < 8; ++g)
        if (!((kmask >> g) & 1u) && s_gs[wid][g] > bv) { bv = s_gs[wid][g]; bg = g; }
      kmask |= 1u << bg;
    }
    unsigned umask = 0;
    for (int slot = 0; slot < 4; ++slot) {
      int be = 0; double bv = -1.0;
      for (int ee = 0; ee < 32; ++ee)
        if (((kmask >> (ee >> 2)) & 1u) && !((umask >> ee) & 1u) && s_sc[wid][ee] > bv) {
          bv = s_sc[wid][ee]; be = ee;
        }
      umask |= 1u << be;
      idx[t * 4 + slot] = be;
      wts[t * 4 + slot] = (float)bv;
    }
  }
}

// ------------------------------------------------- dispatch bookkeeping ----
__global__ __launch_bounds__(256) void count_kernel(const int* __restrict__ idx,
                                                    int* __restrict__ meta) {
  __shared__ int h[32];
  int tid = threadIdx.x;
  if (tid < 32) h[tid] = 0;
  __syncthreads();
  atomicAdd(&h[idx[blockIdx.x * 256 + tid]], 1);
  __syncthreads();
  if (tid < 32 && h[tid]) atomicAdd(&meta[tid], h[tid]);
}

__global__ void scan_kernel(int* __restrict__ meta) {
  int lane = threadIdx.x & 63;
  if (lane < 32) {
    int c = meta[lane];
    int pre = c;
    #pragma unroll
    for (int d = 1; d < 32; d <<= 1) { int t = __shfl_up(pre, d); if (lane >= d) pre += t; }
    int excl = pre - c;
    meta[64 + lane] = excl;
    meta[32 + lane] = excl;
    int nt = (c + 255) >> 8;                      // 256-row tiles now
    int ntp = nt;
    #pragma unroll
    for (int d = 1; d < 32; d <<= 1) { int t = __shfl_up(ntp, d); if (lane >= d) ntp += t; }
    int ntExcl = ntp - nt;
    for (int k = 0; k < nt; ++k) { meta[128 + ntExcl + k] = lane; meta[1184 + ntExcl + k] = k << 8; }
    if (lane == 31) { meta[96] = excl + c; meta[97] = ntExcl + nt; }
  }
}

__global__ __launch_bounds__(256) void scatter_kernel(
    const int* __restrict__ idx, int* __restrict__ meta,
    int* __restrict__ tok, int* __restrict__ inv) {
  int i = blockIdx.x * 256 + threadIdx.x;
  int lane = threadIdx.x & 63;
  int e = idx[i];
  unsigned long long m = ~0ull;
  #pragma unroll
  for (int b = 0; b < 5; ++b) {
    unsigned long long vote = __ballot((e >> b) & 1);
    m &= ((e >> b) & 1) ? vote : ~vote;
  }
  int leader = __ffsll((long long)m) - 1;
  int rank = __popcll(m & ((1ull << lane) - 1));
  int base = 0;
  if (lane == leader) base = atomicAdd(&meta[32 + e], (int)__popcll(m));
  base = __shfl(base, leader);
  int p = base + rank;
  tok[p] = i >> 2;
  inv[i] = p;
}

// ----------------------------------------------------------- repacking ----
__global__ __launch_bounds__(256) void repack_kernel(
    const float* __restrict__ src, unsigned short* __restrict__ dst,
    int K, int N, int tilesPerMat) {
  const int w = blockIdx.x * 4 + (threadIdx.x >> 6);
  const int j = threadIdx.x & 63;
  const int e = w / tilesPerMat, rem = w % tilesPerMat;
  const int kSteps = K >> 5;
  const int nt = rem / kSteps, kq = rem % kSteps;
  const float* s = src + (size_t)e * K * N + (size_t)(kq * 32) * N + nt * 64 + j;
  float v[32];
  #pragma unroll
  for (int kk = 0; kk < 32; ++kk) v[kk] = s[(size_t)kk * N];
  char* d = (char*)dst + (size_t)w * 4096 + j * 64;
  const int sz = (j & 3) ^ ((j >> 2) & 3);
  #pragma unroll
  for (int q = 0; q < 4; ++q) {
    int o = (q ^ sz) * 8;
    uint4 tv;
    tv.x = f2bf2(v[o + 0], v[o + 1]);
    tv.y = f2bf2(v[o + 2], v[o + 3]);
    tv.z = f2bf2(v[o + 4], v[o + 5]);
    tv.w = f2bf2(v[o + 6], v[o + 7]);
    *(uint4*)(d + q * 16) = tv;
  }
}

__global__ __launch_bounds__(256) void repack13_kernel(
    const float* __restrict__ src1, const float* __restrict__ src3,
    unsigned short* __restrict__ dst, int K, int N, int jtTiles) {
  const int w = blockIdx.x * 4 + (threadIdx.x >> 6);
  const int j = threadIdx.x & 63;
  const int kSteps = K >> 5;
  const int tpm = jtTiles * kSteps;
  const int e = w / tpm, rem = w % tpm;
  const int jt = rem / kSteps, kq = rem % kSteps;
  const int jg = jt * 64 + j;
  const int c = ((jg >> 5) << 4) + (jg & 15);
  const float* s = (((jg >> 4) & 1) ? src3 : src1)
                 + (size_t)e * K * N + (size_t)(kq * 32) * N + c;
  float v[32];
  #pragma unroll
  for (int kk = 0; kk < 32; ++kk) v[kk] = s[(size_t)kk * N];
  char* d = (char*)dst + (size_t)w * 4096 + j * 64;
  const int sz = (j & 3) ^ ((j >> 2) & 3);
  #pragma unroll
  for (int q = 0; q < 4; ++q) {
    int o = (q ^ sz) * 8;
    uint4 tv;
    tv.x = f2bf2(v[o + 0], v[o + 1]);
    tv.y = f2bf2(v[o + 2], v[o + 3]);
    tv.z = f2bf2(v[o + 4], v[o + 5]);
    tv.w = f2bf2(v[o + 6], v[o + 7]);
    *(uint4*)(d + q * 16) = tv;
  }
}

// ============== 256x256 8-phase GEMM core (BK=64, 128KB LDS ring) ==========
// 512 thr / 8 waves (wm=wave>>2 in {0,1}, wn=wave&3). Per-wave C: 128x64,
// acc[8][4] (row = wm*128 + (m8>>2)*64 + (m8&3)*16 + g*4 + r, col =
// wn*64 + ni*16 + f). LDS: 4 ring slots x 32KB; slot = unit(kt,kk):
// A [mt4][64rows][64B] + B@16384 [nt4][64cols][64B], 16B sub-slot q holds
// k-octet q^sz(row&63). Phase p (0..7): reads slot p>>1 (chalf=p&1),
// stages 2 gl16 into slot (p>>1+3)&3 for unit I*4+3+(p>>1); vmcnt(8) at the
// end of every odd phase (12 outstanding -> wait oldest 4). Never drains.

#define G8_PRE()                                                              \
  const int tid = threadIdx.x, lane = tid & 63, wave = tid >> 6;              \
  const int wm = wave >> 2, wn = wave & 3;                                    \
  const int f = lane & 15, g = lane >> 4;                                     \
  const int wud = wave >> 2, wlo = wave & 3;                                  \
  const int row_in = wlo * 16 + (lane >> 2);                                  \
  const int szr = (row_in & 3) ^ ((row_in >> 2) & 3);                         \
  const int qs = (((lane & 3) ^ szr) << 4);                                   \
  const int btile_off = wlo * 1024 + lane * 16;                               \
  const int wv1k = wave * 1024;                                               \
  const int awb = wm * 8192;                                                  \
  const int wn4 = wn * 4096;                                                  \
  int aoff[4];                                                                \
  _Pragma("unroll")                                                           \
  for (int ii = 0; ii < 4; ++ii) {                                            \
    int u16 = ii * 16 + f;                                                    \
    aoff[ii] = u16 * 64 + ((g ^ ((u16 & 3) ^ ((u16 >> 2) & 3))) << 4);        \
  }                                                                           \
  f32x4 acc[8][4];                                                            \
  const f32x4 zz = {0.f, 0.f, 0.f, 0.f};                                      \
  _Pragma("unroll")                                                           \
  for (int mi = 0; mi < 8; ++mi)                                              \
    _Pragma("unroll")                                                         \
    for (int ni = 0; ni < 4; ++ni) acc[mi][ni] = zz;

#define G8_PH(p, UMAXv)                                                       \
  {                                                                           \
    const char* sb_ = lds + ((p) >> 1) * 32768;                               \
    const char* ab_ = sb_ + awb + ((p) & 1) * 4096;                           \
    const char* bb_ = sb_ + 16384 + wn4;                                      \
    bf16x8 af_[4], bv_[4];                                                    \
    _Pragma("unroll")                                                         \
    for (int mi = 0; mi < 4; ++mi) af_[mi] = *(const bf16x8*)(ab_ + aoff[mi]);\
    _Pragma("unroll")                                                         \
    for (int ni = 0; ni < 4; ++ni) bv_[ni] = *(const bf16x8*)(bb_ + aoff[ni]);\
    int u_ = I4 + 3 + ((p) >> 1);                                             \
    if (u_ >= (UMAXv)) u_ = (UMAXv) - 1;                                      \
    char* td_ = lds + (((((p) >> 1) + 3) & 3) * 32768);                       \
    if ((p) & 1) {                                                            \
      gl16(pB0 + (size_t)u_ * 4096, td_ + 16384 + wv1k);                      \
      gl16(pB1 + (size_t)u_ * 4096, td_ + 24576 + wv1k);                      \
    } else {                                                                  \
      gl16(pA0 + u_ * 64, td_ + wv1k);                                        \
      gl16(pA1 + u_ * 64, td_ + 8192 + wv1k);                                 \
    }                                                                         \
    BARX();                                                                   \
    __builtin_amdgcn_s_setprio(1);                                            \
    _Pragma("unroll")                                                         \
    for (int ni = 0; ni < 4; ++ni)                                            \
      _Pragma("unroll")                                                       \
      for (int mi = 0; mi < 4; ++mi)                                          \
        acc[((p) & 1) * 4 + mi][ni] = __builtin_amdgcn_mfma_f32_16x16x32_bf16(\
            af_[mi], bv_[ni], acc[((p) & 1) * 4 + mi][ni], 0, 0, 0);          \
    __builtin_amdgcn_s_setprio(0);                                            \
    if ((p) & 1) asm volatile("s_waitcnt vmcnt(8)" ::: "memory");             \
    BARX();                                                                   \
  }

#define G8_BODY(UMAXv)                                                        \
  _Pragma("unroll")                                                           \
  for (int uu = 0; uu < 3; ++uu) {                                            \
    gl16(pA0 + uu * 64, lds + uu * 32768 + wv1k);                             \
    gl16(pA1 + uu * 64, lds + uu * 32768 + 8192 + wv1k);                      \
    gl16(pB0 + (size_t)uu * 4096, lds + uu * 32768 + 16384 + wv1k);           \
    gl16(pB1 + (size_t)uu * 4096, lds + uu * 32768 + 24576 + wv1k);           \
  }                                                                           \
  asm volatile("s_waitcnt vmcnt(8)" ::: "memory");                            \
  BARX();                                                                     \
  for (int I = 0; I < (UMAXv) / 4; ++I) {                                     \
    const int I4 = I * 4;                                                     \
    G8_PH(0, UMAXv); G8_PH(1, UMAXv); G8_PH(2, UMAXv); G8_PH(3, UMAXv);       \
    G8_PH(4, UMAXv); G8_PH(5, UMAXv); G8_PH(6, UMAXv); G8_PH(7, UMAXv);       \
  }

// --------------------------------------------------------- shared GEMM1 ----
__global__ __launch_bounds__(512, 2) void s1_kernel(
    const unsigned short* __restrict__ xb, const unsigned short* __restrict__ w13,
    const float* __restrict__ sb1, const float* __restrict__ sb3,
    unsigned short* __restrict__ Hs) {
  __shared__ char lds[131072];
  const int m0 = blockIdx.y * 256;
  G8_PRE();
  const char* pA0 = (const char*)xb + (size_t)(m0 + wud * 64 + row_in) * 2048 + qs;
  const char* pA1 = pA0 + (size_t)128 * 2048;
  const char* pB0 = (const char*)w13 + ((size_t)(blockIdx.x * 4 + wud) * 32) * 4096 + btile_off;
  const char* pB1 = (const char*)w13 + ((size_t)(blockIdx.x * 4 + 2 + wud) * 32) * 4096 + btile_off;
  G8_BODY(32);
  const int colb = blockIdx.x * 128;
  #pragma unroll
  for (int p2 = 0; p2 < 2; ++p2) {
    int c = colb + wn * 32 + p2 * 16 + f;
    float bb1 = sb1[c], bb3 = sb3[c];
    #pragma unroll
    for (int m8 = 0; m8 < 8; ++m8) {
      int row = m0 + wm * 128 + (m8 >> 2) * 64 + (m8 & 3) * 16 + g * 4;
      #pragma unroll
      for (int r = 0; r < 4; ++r) {
        float v1 = acc[m8][2 * p2][r] + bb1;
        float v3 = acc[m8][2 * p2 + 1][r] + bb3;
        float h = (v1 / (1.f + __expf(-v1))) * v3;
        Hs[(size_t)(row + r) * 1024 + c] = f2bf(h);
      }
    }
  }
}

// --------------------------------------------------------- shared GEMM2 ----
__global__ __launch_bounds__(512, 2) void s2_kernel(
    const unsigned short* __restrict__ Hs, const unsigned short* __restrict__ b2i,
    const float* __restrict__ sb2, float* __restrict__ out) {
  __shared__ char lds[131072];
  const int m0 = blockIdx.y * 256;
  G8_PRE();
  const char* pA0 = (const char*)Hs + (size_t)(m0 + wud * 64 + row_in) * 2048 + qs;
  const char* pA1 = pA0 + (size_t)128 * 2048;
  const char* pB0 = (const char*)b2i + ((size_t)(blockIdx.x * 4 + wud) * 32) * 4096 + btile_off;
  const char* pB1 = (const char*)b2i + ((size_t)(blockIdx.x * 4 + 2 + wud) * 32) * 4096 + btile_off;
  G8_BODY(32);
  #pragma unroll
  for (int ni = 0; ni < 4; ++ni) {
    int c = blockIdx.x * 256 + wn * 64 + ni * 16 + f;
    float bb = sb2[c];
    #pragma unroll
    for (int m8 = 0; m8 < 8; ++m8) {
      int row = m0 + wm * 128 + (m8 >> 2) * 64 + (m8 & 3) * 16 + g * 4;
      #pragma unroll
      for (int r = 0; r < 4; ++r)
        out[(size_t)(row + r) * 1024 + c] = acc[m8][ni][r] + bb;
    }
  }
}

// --------------------------------------------------------- routed GEMM1 ----
__global__ __launch_bounds__(512, 2) void g1_kernel(
    const unsigned short* __restrict__ xb, const unsigned short* __restrict__ w13,
    const float* __restrict__ b1, const float* __restrict__ b3,
    const int* __restrict__ tok, const int* __restrict__ meta,
    unsigned short* __restrict__ H) {
  __shared__ char lds[131072];
  if ((int)blockIdx.y >= meta[97]) return;
  const int e = meta[128 + blockIdx.y], m0 = meta[1184 + blockIdx.y];
  const int off_e = meta[64 + e], nrem = meta[e] - m0;
  G8_PRE();
  const int r0a = wud * 64 + row_in;
  const int ix0 = off_e + m0 + ((r0a < nrem) ? r0a : 0);
  const int ix1 = off_e + m0 + ((r0a + 128 < nrem) ? r0a + 128 : 0);
  const char* pA0 = (const char*)xb + (size_t)tok[ix0] * 2048 + qs;
  const char* pA1 = (const char*)xb + (size_t)tok[ix1] * 2048 + qs;
  const char* pB0 = (const char*)w13 + ((size_t)(e * 16 + blockIdx.x * 4 + wud) * 32) * 4096 + btile_off;
  const char* pB1 = (const char*)w13 + ((size_t)(e * 16 + blockIdx.x * 4 + 2 + wud) * 32) * 4096 + btile_off;
  G8_BODY(32);
  const int colb = blockIdx.x * 128;
  #pragma unroll
  for (int p2 = 0; p2 < 2; ++p2) {
    int c = colb + wn * 32 + p2 * 16 + f;
    float bb1 = b1[e * 512 + c], bb3 = b3[e * 512 + c];
    #pragma unroll
    for (int m8 = 0; m8 < 8; ++m8) {
      int row = wm * 128 + (m8 >> 2) * 64 + (m8 & 3) * 16 + g * 4;
      #pragma unroll
      for (int r = 0; r < 4; ++r) {
        if (row + r < nrem) {
          float v1 = acc[m8][2 * p2][r] + bb1;
          float v3 = acc[m8][2 * p2 + 1][r] + bb3;
          float h = (v1 / (1.f + __expf(-v1))) * v3;
          H[(size_t)(off_e + m0 + row + r) * 512 + c] = f2bf(h);
        }
      }
    }
  }
}

// --------------------------------------------------------- routed GEMM2 ----
__global__ __launch_bounds__(512, 2) void g2_kernel(
    const unsigned short* __restrict__ H, const unsigned short* __restrict__ w2i,
    const float* __restrict__ b2, const int* __restrict__ meta,
    unsigned short* __restrict__ Y, int cbase) {
  __shared__ char lds[131072];
  if ((int)blockIdx.y >= meta[97]) return;
  const int e = meta[128 + blockIdx.y], m0 = meta[1184 + blockIdx.y];
  const int off_e = meta[64 + e], nrem = meta[e] - m0;
  G8_PRE();
  const int r0a = wud * 64 + row_in;
  const int ix0 = off_e + m0 + ((r0a < nrem) ? r0a : 0);
  const int ix1 = off_e + m0 + ((r0a + 128 < nrem) ? r0a + 128 : 0);
  const char* pA0 = (const char*)H + (size_t)ix0 * 1024 + qs;
  const char* pA1 = (const char*)H + (size_t)ix1 * 1024 + qs;
  const int nt0 = (cbase >> 6) + blockIdx.x * 4;
  const char* pB0 = (const char*)w2i + ((size_t)(e * 16 + nt0 + wud) * 16) * 4096 + btile_off;
  const char* pB1 = (const char*)w2i + ((size_t)(e * 16 + nt0 + 2 + wud) * 16) * 4096 + btile_off;
  G8_BODY(16);
  #pragma unroll
  for (int ni = 0; ni < 4; ++ni) {
    int ycol = blockIdx.x * 256 + wn * 64 + ni * 16 + f;
    float bb = b2[e * 1024 + cbase + ycol];
    #pragma unroll
    for (int m8 = 0; m8 < 8; ++m8) {
      int row = wm * 128 + (m8 >> 2) * 64 + (m8 & 3) * 16 + g * 4;
      #pragma unroll
      for (int r = 0; r < 4; ++r) {
        if (row + r < nrem)
          Y[(size_t)(off_e + m0 + row + r) * 512 + ycol] = f2bf(acc[m8][ni][r] + bb);
      }
    }
  }
}

// ------------------------------------------------------------- combine ----
__global__ __launch_bounds__(256) void combine_kernel(
    const unsigned short* __restrict__ Y, const int* __restrict__ inv,
    const float* __restrict__ wts, float* __restrict__ out, int cbase) {
  int t = blockIdx.x * 2 + (threadIdx.x >> 7);
  int c = (threadIdx.x & 127) * 4;
  int4 iv = *(const int4*)(inv + t * 4);
  float4 wv = *(const float4*)(wts + t * 4);
  float* op = out + (size_t)t * 1024 + cbase + c;
  float4 o = *(float4*)op;
  uint2 u;
  u = *(const uint2*)(Y + (size_t)iv.x * 512 + c);
  o.x += wv.x * bflo(u.x); o.y += wv.x * bfhi(u.x);
  o.z += wv.x * bflo(u.y); o.w += wv.x * bfhi(u.y);
  u = *(const uint2*)(Y + (size_t)iv.y * 512 + c);
  o.x += wv.y * bflo(u.x); o.y += wv.y * bfhi(u.x);
  o.z += wv.y * bflo(u.y); o.w += wv.y * bfhi(u.y);
  u = *(const uint2*)(Y + (size_t)iv.z * 512 + c);
  o.x += wv.z * bflo(u.x); o.y += wv.z * bfhi(u.x);
  o.z += wv.z * bflo(u.y); o.w += wv.z * bfhi(u.y);
  u = *(const uint2*)(Y + (size_t)iv.w * 512 + c);
  o.x += wv.w * bflo(u.x); o.y += wv.w * bfhi(u.x);
  o.z += wv.w * bflo(u.y); o.w += wv.w * bfhi(u.y);
  *(float4*)op = o;
}

// ------------------------------------------------------------------ host ----
extern "C" void kernel_launch(void* const* d_in, const int* in_sizes, int n_in,
                              void* d_out, int out_size, void* d_ws, size_t ws_size,
                              hipStream_t stream) {
  const float* x   = (const float*)d_in[0];
  const float* gw  = (const float*)d_in[1];
  const float* gb  = (const float*)d_in[2];
  const float* w1  = (const float*)d_in[3];
  const float* b1  = (const float*)d_in[4];
  const float* w3  = (const float*)d_in[5];
  const float* b3  = (const float*)d_in[6];
  const float* w2  = (const float*)d_in[7];
  const float* b2  = (const float*)d_in[8];
  const float* sw1 = (const float*)d_in[9];
  const float* sb1 = (const float*)d_in[10];
  const float* sw3 = (const float*)d_in[11];
  const float* sb3 = (const float*)d_in[12];
  const float* sw2 = (const float*)d_in[13];
  const float* sb2 = (const float*)d_in[14];
  float* out = (float*)d_out;
  char* ws = (char*)d_ws;

  const size_t OFF_XB   = 134217728;
  const size_t OFF_W13I = 201326592;            // 64 MiB
  const size_t OFF_W2I  = 268435456;            // 32 MiB
  const size_t OFF_S13I = 301989888;            // 4 MiB
  const size_t OFF_SW2I = 306184192;            // 2 MiB
  const size_t OFF_IDX  = 308281344;
  const size_t OFF_WTS  = 308805632;
  const size_t OFF_TOK  = 309329920;
  const size_t OFF_INV  = 309854208;
  const size_t OFF_META = 310378496;
  if (ws_size < OFF_META + 8960) return;

  unsigned short* H    = (unsigned short*)ws;
  unsigned short* xb   = (unsigned short*)(ws + OFF_XB);
  unsigned short* Yb   = (unsigned short*)(ws + OFF_XB);   // aliases xb+w13i
  unsigned short* w13i = (unsigned short*)(ws + OFF_W13I);
  unsigned short* w2i  = (unsigned short*)(ws + OFF_W2I);
  unsigned short* s13i = (unsigned short*)(ws + OFF_S13I);
  unsigned short* sw2i = (unsigned short*)(ws + OFF_SW2I);
  int*   idx  = (int*)(ws + OFF_IDX);
  float* wts  = (float*)(ws + OFF_WTS);
  int*   tokl = (int*)(ws + OFF_TOK);
  int*   inv  = (int*)(ws + OFF_INV);
  int*   meta = (int*)(ws + OFF_META);

  hipMemsetAsync(meta, 0, 128, stream);
  gate_kernel<<<dim3(8192), dim3(256), 0, stream>>>(x, gw, gb, idx, wts, xb);
  count_kernel<<<dim3(512), dim3(256), 0, stream>>>(idx, meta);
  scan_kernel<<<dim3(1), dim3(64), 0, stream>>>(meta);
  scatter_kernel<<<dim3(512), dim3(256), 0, stream>>>(idx, meta, tokl, inv);
  repack13_kernel<<<dim3(4096), dim3(256), 0, stream>>>(w1, w3, w13i, 1024, 512, 16);
  repack_kernel<<<dim3(2048), dim3(256), 0, stream>>>(w2, w2i, 512, 1024, 256);
  repack13_kernel<<<dim3(256), dim3(256), 0, stream>>>(sw1, sw3, s13i, 1024, 1024, 32);
  repack_kernel<<<dim3(128), dim3(256), 0, stream>>>(sw2, sw2i, 1024, 1024, 512);
  s1_kernel<<<dim3(8, 128), dim3(512), 0, stream>>>(xb, s13i, sb1, sb3, H);
  s2_kernel<<<dim3(4, 128), dim3(512), 0, stream>>>(H, sw2i, sb2, out);
  g1_kernel<<<dim3(4, 544), dim3(512), 0, stream>>>(xb, w13i, b1, b3, tokl, meta, H);
  g2_kernel<<<dim3(2, 544), dim3(512), 0, stream>>>(H, w2i, b2, meta, Yb, 0);
  combine_kernel<<<dim3(16384), dim3(256), 0, stream>>>(Yb, inv, wts, out, 0);
  g2_kernel<<<dim3(2, 544), dim3(512), 0, stream>>>(H, w2i, b2, meta, Yb, 512);
  combine_kernel<<<dim3(16384), dim3(256), 0, stream>>>(Yb, inv, wts, out, 512);
}

// Round 8
// 1592.497 us; speedup vs baseline: 1.0847x; 1.0307x over previous
//
#include <hip/hip_runtime.h>
#include <stdint.h>

#define DIM_    1024
#define INTER_  512

typedef short bf16x4 __attribute__((ext_vector_type(4)));
typedef short bf16x8 __attribute__((ext_vector_type(8)));
typedef float f32x4  __attribute__((ext_vector_type(4)));

__device__ __forceinline__ unsigned short f2bf(float f) {
  union { float f; unsigned u; } v; v.f = f;
  return (unsigned short)((v.u + 0x7FFFu + ((v.u >> 16) & 1u)) >> 16);
}
__device__ __forceinline__ unsigned f2bf2(float a, float b) {
  union { float f; unsigned u; } va, vb; va.f = a; vb.f = b;
  unsigned ra = (va.u + 0x7FFFu + ((va.u >> 16) & 1u)) >> 16;
  unsigned rb = (vb.u + 0x7FFFu + ((vb.u >> 16) & 1u)) >> 16;
  return ra | (rb << 16);
}
__device__ __forceinline__ float bfhi(unsigned u) {
  union { unsigned u; float f; } v; v.u = u & 0xffff0000u; return v.f;
}
__device__ __forceinline__ float bflo(unsigned u) {
  union { unsigned u; float f; } v; v.u = u << 16; return v.f;
}

__device__ __forceinline__ void gl16(const void* g, void* l) {
  __builtin_amdgcn_global_load_lds(
      (const __attribute__((address_space(1))) unsigned int*)g,
      (__attribute__((address_space(3))) unsigned int*)l, 16, 0, 0);
}

#define BARX() do { asm volatile("" ::: "memory"); \
                    __builtin_amdgcn_s_barrier();  \
                    asm volatile("" ::: "memory"); } while (0)

// ---------------------------------------------------------------- gate ----
__global__ __launch_bounds__(256) void gate_kernel(
    const float* __restrict__ x, const float* __restrict__ gw,
    const float* __restrict__ gb, int* __restrict__ idx, float* __restrict__ wts,
    unsigned short* __restrict__ xb) {
  __shared__ double s_sc[4][32];
  __shared__ double s_gs[4][8];
  const int wid = threadIdx.x >> 6, lane = threadIdx.x & 63;
  const int t = blockIdx.x * 4 + wid;
  {
    const float* xrow = x + (size_t)t * DIM_ + lane * 16;
    unsigned short* xbrow = xb + (size_t)t * DIM_ + lane * 16;
    float4 f0 = *(const float4*)(xrow);
    float4 f1 = *(const float4*)(xrow + 4);
    float4 f2v = *(const float4*)(xrow + 8);
    float4 f3v = *(const float4*)(xrow + 12);
    uint4 o0, o1;
    o0.x = f2bf2(f0.x, f0.y);  o0.y = f2bf2(f0.z, f0.w);
    o0.z = f2bf2(f1.x, f1.y);  o0.w = f2bf2(f1.z, f1.w);
    o1.x = f2bf2(f2v.x, f2v.y); o1.y = f2bf2(f2v.z, f2v.w);
    o1.z = f2bf2(f3v.x, f3v.y); o1.w = f2bf2(f3v.z, f3v.w);
    *(uint4*)(xbrow) = o0;
    *(uint4*)(xbrow + 8) = o1;
  }
  const int e = lane & 31, half = lane >> 5;
  const float* xr  = x  + (size_t)t * DIM_ + half * 512;
  const float* gwp = gw + (size_t)half * 512 * 32 + e;
  double a0 = 0, a1 = 0, a2 = 0, a3 = 0;
  for (int k = 0; k < 512; k += 4) {
    float4 xv = *(const float4*)(xr + k);
    a0 += (double)xv.x * (double)gwp[(k + 0) * 32];
    a1 += (double)xv.y * (double)gwp[(k + 1) * 32];
    a2 += (double)xv.z * (double)gwp[(k + 2) * 32];
    a3 += (double)xv.w * (double)gwp[(k + 3) * 32];
  }
  double lg = (a0 + a1) + (a2 + a3);
  lg += __shfl_xor(lg, 32);
  lg += (double)gb[e];
  double m = lg;
  #pragma unroll
  for (int d = 1; d < 32; d <<= 1) m = fmax(m, __shfl_xor(m, d));
  double ex = exp(lg - m);
  double ssum = ex;
  #pragma unroll
  for (int d = 1; d < 32; d <<= 1) ssum += __shfl_xor(ssum, d);
  double sc = ex / ssum;
  double p  = __shfl_xor(sc, 1);
  double m1 = fmax(sc, p), n1 = fmin(sc, p);
  double m2 = __shfl_xor(m1, 2), n2 = __shfl_xor(n1, 2);
  double gs = (m1 >= m2) ? (m1 + fmax(n1, m2)) : (m2 + fmax(n2, m1));
  if (lane < 32) {
    s_sc[wid][e] = sc;
    if ((e & 3) == 0) s_gs[wid][e >> 2] = gs;
  }
  __syncthreads();
  if (lane == 0) {
    unsigned kmask = 0;
    for (int it = 0; it < 4; ++it) {
      int bg = 0; double bv = -1.0;
      for (int g = 0; g < 8; ++g)
        if (!((kmask >> g) & 1u) && s_gs[wid][g] > bv) { bv = s_gs[wid][g]; bg = g; }
      kmask |= 1u << bg;
    }
    unsigned umask = 0;
    for (int slot = 0; slot < 4; ++slot) {
      int be = 0; double bv = -1.0;
      for (int ee = 0; ee < 32; ++ee)
        if (((kmask >> (ee >> 2)) & 1u) && !((umask >> ee) & 1u) && s_sc[wid][ee] > bv) {
          bv = s_sc[wid][ee]; be = ee;
        }
      umask |= 1u << be;
      idx[t * 4 + slot] = be;
      wts[t * 4 + slot] = (float)bv;
    }
  }
}

// ------------------------------------------------- dispatch bookkeeping ----
__global__ __launch_bounds__(256) void count_kernel(const int* __restrict__ idx,
                                                    int* __restrict__ meta) {
  __shared__ int h[32];
  int tid = threadIdx.x;
  if (tid < 32) h[tid] = 0;
  __syncthreads();
  atomicAdd(&h[idx[blockIdx.x * 256 + tid]], 1);
  __syncthreads();
  if (tid < 32 && h[tid]) atomicAdd(&meta[tid], h[tid]);
}

__global__ void scan_kernel(int* __restrict__ meta) {
  int lane = threadIdx.x & 63;
  if (lane < 32) {
    int c = meta[lane];
    int pre = c;
    #pragma unroll
    for (int d = 1; d < 32; d <<= 1) { int t = __shfl_up(pre, d); if (lane >= d) pre += t; }
    int excl = pre - c;
    meta[64 + lane] = excl;
    meta[32 + lane] = excl;
    int nt = (c + 255) >> 8;
    int ntp = nt;
    #pragma unroll
    for (int d = 1; d < 32; d <<= 1) { int t = __shfl_up(ntp, d); if (lane >= d) ntp += t; }
    int ntExcl = ntp - nt;
    for (int k = 0; k < nt; ++k) { meta[128 + ntExcl + k] = lane; meta[1184 + ntExcl + k] = k << 8; }
    if (lane == 31) { meta[96] = excl + c; meta[97] = ntExcl + nt; }
  }
}

__global__ __launch_bounds__(256) void scatter_kernel(
    const int* __restrict__ idx, int* __restrict__ meta,
    int* __restrict__ tok, int* __restrict__ inv) {
  int i = blockIdx.x * 256 + threadIdx.x;
  int lane = threadIdx.x & 63;
  int e = idx[i];
  unsigned long long m = ~0ull;
  #pragma unroll
  for (int b = 0; b < 5; ++b) {
    unsigned long long vote = __ballot((e >> b) & 1);
    m &= ((e >> b) & 1) ? vote : ~vote;
  }
  int leader = __ffsll((long long)m) - 1;
  int rank = __popcll(m & ((1ull << lane) - 1));
  int base = 0;
  if (lane == leader) base = atomicAdd(&meta[32 + e], (int)__popcll(m));
  base = __shfl(base, leader);
  int p = base + rank;
  tok[p] = i >> 2;
  inv[i] = p;
}

// ----------------------------------------------------------- repacking ----
__global__ __launch_bounds__(256) void repack_kernel(
    const float* __restrict__ src, unsigned short* __restrict__ dst,
    int K, int N, int tilesPerMat) {
  const int w = blockIdx.x * 4 + (threadIdx.x >> 6);
  const int j = threadIdx.x & 63;
  const int e = w / tilesPerMat, rem = w % tilesPerMat;
  const int kSteps = K >> 5;
  const int nt = rem / kSteps, kq = rem % kSteps;
  const float* s = src + (size_t)e * K * N + (size_t)(kq * 32) * N + nt * 64 + j;
  float v[32];
  #pragma unroll
  for (int kk = 0; kk < 32; ++kk) v[kk] = s[(size_t)kk * N];
  char* d = (char*)dst + (size_t)w * 4096 + j * 64;
  const int sz = (j & 3) ^ ((j >> 2) & 3);
  #pragma unroll
  for (int q = 0; q < 4; ++q) {
    int o = (q ^ sz) * 8;
    uint4 tv;
    tv.x = f2bf2(v[o + 0], v[o + 1]);
    tv.y = f2bf2(v[o + 2], v[o + 3]);
    tv.z = f2bf2(v[o + 4], v[o + 5]);
    tv.w = f2bf2(v[o + 6], v[o + 7]);
    *(uint4*)(d + q * 16) = tv;
  }
}

__global__ __launch_bounds__(256) void repack13_kernel(
    const float* __restrict__ src1, const float* __restrict__ src3,
    unsigned short* __restrict__ dst, int K, int N, int jtTiles) {
  const int w = blockIdx.x * 4 + (threadIdx.x >> 6);
  const int j = threadIdx.x & 63;
  const int kSteps = K >> 5;
  const int tpm = jtTiles * kSteps;
  const int e = w / tpm, rem = w % tpm;
  const int jt = rem / kSteps, kq = rem % kSteps;
  const int jg = jt * 64 + j;
  const int c = ((jg >> 5) << 4) + (jg & 15);
  const float* s = (((jg >> 4) & 1) ? src3 : src1)
                 + (size_t)e * K * N + (size_t)(kq * 32) * N + c;
  float v[32];
  #pragma unroll
  for (int kk = 0; kk < 32; ++kk) v[kk] = s[(size_t)kk * N];
  char* d = (char*)dst + (size_t)w * 4096 + j * 64;
  const int sz = (j & 3) ^ ((j >> 2) & 3);
  #pragma unroll
  for (int q = 0; q < 4; ++q) {
    int o = (q ^ sz) * 8;
    uint4 tv;
    tv.x = f2bf2(v[o + 0], v[o + 1]);
    tv.y = f2bf2(v[o + 2], v[o + 3]);
    tv.z = f2bf2(v[o + 4], v[o + 5]);
    tv.w = f2bf2(v[o + 6], v[o + 7]);
    *(uint4*)(d + q * 16) = tv;
  }
}

// ============== 256x256 8-phase GEMM core (BK=64, 128KB LDS ring) ==========
// B-fragments loaded once per phase-pair (even phase) and reused in the odd
// phase -> 8/4 ds_read_b128 per phase instead of 8/8 (-25% LDS read BW).
// XCD-chunked flat-grid swizzle applied in each kernel (nwg % 8 == 0).

#define G8_PRE()                                                              \
  const int tid = threadIdx.x, lane = tid & 63, wave = tid >> 6;              \
  const int wm = wave >> 2, wn = wave & 3;                                    \
  const int f = lane & 15, g = lane >> 4;                                     \
  const int wud = wave >> 2, wlo = wave & 3;                                  \
  const int row_in = wlo * 16 + (lane >> 2);                                  \
  const int szr = (row_in & 3) ^ ((row_in >> 2) & 3);                         \
  const int qs = (((lane & 3) ^ szr) << 4);                                   \
  const int btile_off = wlo * 1024 + lane * 16;                               \
  const int wv1k = wave * 1024;                                               \
  const int awb = wm * 8192;                                                  \
  const int wn4 = wn * 4096;                                                  \
  int aoff[4];                                                                \
  _Pragma("unroll")                                                           \
  for (int ii = 0; ii < 4; ++ii) {                                            \
    int u16 = ii * 16 + f;                                                    \
    aoff[ii] = u16 * 64 + ((g ^ ((u16 & 3) ^ ((u16 >> 2) & 3))) << 4);        \
  }                                                                           \
  bf16x8 bvp[4];                                                              \
  f32x4 acc[8][4];                                                            \
  const f32x4 zz = {0.f, 0.f, 0.f, 0.f};                                      \
  _Pragma("unroll")                                                           \
  for (int mi = 0; mi < 8; ++mi)                                              \
    _Pragma("unroll")                                                         \
    for (int ni = 0; ni < 4; ++ni) acc[mi][ni] = zz;

#define G8_PH(p, UMAXv)                                                       \
  {                                                                           \
    const char* sb_ = lds + ((p) >> 1) * 32768;                               \
    const char* ab_ = sb_ + awb + ((p) & 1) * 4096;                           \
    bf16x8 af_[4];                                                            \
    _Pragma("unroll")                                                         \
    for (int mi = 0; mi < 4; ++mi) af_[mi] = *(const bf16x8*)(ab_ + aoff[mi]);\
    if (!((p) & 1)) {                                                         \
      const char* bb_ = sb_ + 16384 + wn4;                                    \
      _Pragma("unroll")                                                       \
      for (int ni = 0; ni < 4; ++ni)                                          \
        bvp[ni] = *(const bf16x8*)(bb_ + aoff[ni]);                           \
    }                                                                         \
    int u_ = I4 + 3 + ((p) >> 1);                                             \
    if (u_ >= (UMAXv)) u_ = (UMAXv) - 1;                                      \
    char* td_ = lds + (((((p) >> 1) + 3) & 3) * 32768);                       \
    if ((p) & 1) {                                                            \
      gl16(pB0 + (size_t)u_ * 4096, td_ + 16384 + wv1k);                      \
      gl16(pB1 + (size_t)u_ * 4096, td_ + 24576 + wv1k);                      \
    } else {                                                                  \
      gl16(pA0 + u_ * 64, td_ + wv1k);                                        \
      gl16(pA1 + u_ * 64, td_ + 8192 + wv1k);                                 \
    }                                                                         \
    BARX();                                                                   \
    __builtin_amdgcn_s_setprio(1);                                            \
    _Pragma("unroll")                                                         \
    for (int ni = 0; ni < 4; ++ni)                                            \
      _Pragma("unroll")                                                       \
      for (int mi = 0; mi < 4; ++mi)                                          \
        acc[((p) & 1) * 4 + mi][ni] = __builtin_amdgcn_mfma_f32_16x16x32_bf16(\
            af_[mi], bvp[ni], acc[((p) & 1) * 4 + mi][ni], 0, 0, 0);          \
    __builtin_amdgcn_s_setprio(0);                                            \
    if ((p) & 1) asm volatile("s_waitcnt vmcnt(8)" ::: "memory");             \
    BARX();                                                                   \
  }

#define G8_BODY(UMAXv)                                                        \
  _Pragma("unroll")                                                           \
  for (int uu = 0; uu < 3; ++uu) {                                            \
    gl16(pA0 + uu * 64, lds + uu * 32768 + wv1k);                             \
    gl16(pA1 + uu * 64, lds + uu * 32768 + 8192 + wv1k);                      \
    gl16(pB0 + (size_t)uu * 4096, lds + uu * 32768 + 16384 + wv1k);           \
    gl16(pB1 + (size_t)uu * 4096, lds + uu * 32768 + 24576 + wv1k);           \
  }                                                                           \
  asm volatile("s_waitcnt vmcnt(8)" ::: "memory");                            \
  BARX();                                                                     \
  for (int I = 0; I < (UMAXv) / 4; ++I) {                                     \
    const int I4 = I * 4;                                                     \
    G8_PH(0, UMAXv); G8_PH(1, UMAXv); G8_PH(2, UMAXv); G8_PH(3, UMAXv);       \
    G8_PH(4, UMAXv); G8_PH(5, UMAXv); G8_PH(6, UMAXv); G8_PH(7, UMAXv);       \
  }

// XCD-chunked flat swizzle: consecutive work-ids land on the same XCD.
#define XCD_SWZ(GXv)                                                          \
  const int nb_ = gridDim.x;                                                  \
  const int b_ = blockIdx.x;                                                  \
  const int w_ = (b_ & 7) * (nb_ >> 3) + (b_ >> 3);                           \
  const int bx = w_ % (GXv);                                                  \
  const int by = w_ / (GXv);

// --------------------------------------------------------- shared GEMM1 ----
__global__ __launch_bounds__(512, 2) void s1_kernel(
    const unsigned short* __restrict__ xb, const unsigned short* __restrict__ w13,
    const float* __restrict__ sb1, const float* __restrict__ sb3,
    unsigned short* __restrict__ Hs) {
  __shared__ char lds[131072];
  XCD_SWZ(8);
  const int m0 = by * 256;
  G8_PRE();
  const char* pA0 = (const char*)xb + (size_t)(m0 + wud * 64 + row_in) * 2048 + qs;
  const char* pA1 = pA0 + (size_t)128 * 2048;
  const char* pB0 = (const char*)w13 + ((size_t)(bx * 4 + wud) * 32) * 4096 + btile_off;
  const char* pB1 = (const char*)w13 + ((size_t)(bx * 4 + 2 + wud) * 32) * 4096 + btile_off;
  G8_BODY(32);
  const int colb = bx * 128;
  #pragma unroll
  for (int p2 = 0; p2 < 2; ++p2) {
    int c = colb + wn * 32 + p2 * 16 + f;
    float bb1 = sb1[c], bb3 = sb3[c];
    #pragma unroll
    for (int m8 = 0; m8 < 8; ++m8) {
      int row = m0 + wm * 128 + (m8 >> 2) * 64 + (m8 & 3) * 16 + g * 4;
      #pragma unroll
      for (int r = 0; r < 4; ++r) {
        float v1 = acc[m8][2 * p2][r] + bb1;
        float v3 = acc[m8][2 * p2 + 1][r] + bb3;
        float h = (v1 / (1.f + __expf(-v1))) * v3;
        Hs[(size_t)(row + r) * 1024 + c] = f2bf(h);
      }
    }
  }
}

// --------------------------------------------------------- shared GEMM2 ----
__global__ __launch_bounds__(512, 2) void s2_kernel(
    const unsigned short* __restrict__ Hs, const unsigned short* __restrict__ b2i,
    const float* __restrict__ sb2, float* __restrict__ out) {
  __shared__ char lds[131072];
  XCD_SWZ(4);
  const int m0 = by * 256;
  G8_PRE();
  const char* pA0 = (const char*)Hs + (size_t)(m0 + wud * 64 + row_in) * 2048 + qs;
  const char* pA1 = pA0 + (size_t)128 * 2048;
  const char* pB0 = (const char*)b2i + ((size_t)(bx * 4 + wud) * 32) * 4096 + btile_off;
  const char* pB1 = (const char*)b2i + ((size_t)(bx * 4 + 2 + wud) * 32) * 4096 + btile_off;
  G8_BODY(32);
  #pragma unroll
  for (int ni = 0; ni < 4; ++ni) {
    int c = bx * 256 + wn * 64 + ni * 16 + f;
    float bb = sb2[c];
    #pragma unroll
    for (int m8 = 0; m8 < 8; ++m8) {
      int row = m0 + wm * 128 + (m8 >> 2) * 64 + (m8 & 3) * 16 + g * 4;
      #pragma unroll
      for (int r = 0; r < 4; ++r)
        out[(size_t)(row + r) * 1024 + c] = acc[m8][ni][r] + bb;
    }
  }
}

// --------------------------------------------------------- routed GEMM1 ----
__global__ __launch_bounds__(512, 2) void g1_kernel(
    const unsigned short* __restrict__ xb, const unsigned short* __restrict__ w13,
    const float* __restrict__ b1, const float* __restrict__ b3,
    const int* __restrict__ tok, const int* __restrict__ meta,
    unsigned short* __restrict__ H) {
  __shared__ char lds[131072];
  XCD_SWZ(4);
  if (by >= meta[97]) return;
  const int e = meta[128 + by], m0 = meta[1184 + by];
  const int off_e = meta[64 + e], nrem = meta[e] - m0;
  G8_PRE();
  const int r0a = wud * 64 + row_in;
  const int ix0 = off_e + m0 + ((r0a < nrem) ? r0a : 0);
  const int ix1 = off_e + m0 + ((r0a + 128 < nrem) ? r0a + 128 : 0);
  const char* pA0 = (const char*)xb + (size_t)tok[ix0] * 2048 + qs;
  const char* pA1 = (const char*)xb + (size_t)tok[ix1] * 2048 + qs;
  const char* pB0 = (const char*)w13 + ((size_t)(e * 16 + bx * 4 + wud) * 32) * 4096 + btile_off;
  const char* pB1 = (const char*)w13 + ((size_t)(e * 16 + bx * 4 + 2 + wud) * 32) * 4096 + btile_off;
  G8_BODY(32);
  const int colb = bx * 128;
  #pragma unroll
  for (int p2 = 0; p2 < 2; ++p2) {
    int c = colb + wn * 32 + p2 * 16 + f;
    float bb1 = b1[e * 512 + c], bb3 = b3[e * 512 + c];
    #pragma unroll
    for (int m8 = 0; m8 < 8; ++m8) {
      int row = wm * 128 + (m8 >> 2) * 64 + (m8 & 3) * 16 + g * 4;
      #pragma unroll
      for (int r = 0; r < 4; ++r) {
        if (row + r < nrem) {
          float v1 = acc[m8][2 * p2][r] + bb1;
          float v3 = acc[m8][2 * p2 + 1][r] + bb3;
          float h = (v1 / (1.f + __expf(-v1))) * v3;
          H[(size_t)(off_e + m0 + row + r) * 512 + c] = f2bf(h);
        }
      }
    }
  }
}

// --------------------------------------------------------- routed GEMM2 ----
__global__ __launch_bounds__(512, 2) void g2_kernel(
    const unsigned short* __restrict__ H, const unsigned short* __restrict__ w2i,
    const float* __restrict__ b2, const int* __restrict__ meta,
    unsigned short* __restrict__ Y, int cbase) {
  __shared__ char lds[131072];
  XCD_SWZ(2);
  if (by >= meta[97]) return;
  const int e = meta[128 + by], m0 = meta[1184 + by];
  const int off_e = meta[64 + e], nrem = meta[e] - m0;
  G8_PRE();
  const int r0a = wud * 64 + row_in;
  const int ix0 = off_e + m0 + ((r0a < nrem) ? r0a : 0);
  const int ix1 = off_e + m0 + ((r0a + 128 < nrem) ? r0a + 128 : 0);
  const char* pA0 = (const char*)H + (size_t)ix0 * 1024 + qs;
  const char* pA1 = (const char*)H + (size_t)ix1 * 1024 + qs;
  const int nt0 = (cbase >> 6) + bx * 4;
  const char* pB0 = (const char*)w2i + ((size_t)(e * 16 + nt0 + wud) * 16) * 4096 + btile_off;
  const char* pB1 = (const char*)w2i + ((size_t)(e * 16 + nt0 + 2 + wud) * 16) * 4096 + btile_off;
  G8_BODY(16);
  #pragma unroll
  for (int ni = 0; ni < 4; ++ni) {
    int ycol = bx * 256 + wn * 64 + ni * 16 + f;
    float bb = b2[e * 1024 + cbase + ycol];
    #pragma unroll
    for (int m8 = 0; m8 < 8; ++m8) {
      int row = wm * 128 + (m8 >> 2) * 64 + (m8 & 3) * 16 + g * 4;
      #pragma unroll
      for (int r = 0; r < 4; ++r) {
        if (row + r < nrem)
          Y[(size_t)(off_e + m0 + row + r) * 512 + ycol] = f2bf(acc[m8][ni][r] + bb);
      }
    }
  }
}

// ------------------------------------------------------------- combine ----
__global__ __launch_bounds__(256) void combine_kernel(
    const unsigned short* __restrict__ Y, const int* __restrict__ inv,
    const float* __restrict__ wts, float* __restrict__ out, int cbase) {
  int t = blockIdx.x * 2 + (threadIdx.x >> 7);
  int c = (threadIdx.x & 127) * 4;
  int4 iv = *(const int4*)(inv + t * 4);
  float4 wv = *(const float4*)(wts + t * 4);
  float* op = out + (size_t)t * 1024 + cbase + c;
  float4 o = *(float4*)op;
  uint2 u;
  u = *(const uint2*)(Y + (size_t)iv.x * 512 + c);
  o.x += wv.x * bflo(u.x); o.y += wv.x * bfhi(u.x);
  o.z += wv.x * bflo(u.y); o.w += wv.x * bfhi(u.y);
  u = *(const uint2*)(Y + (size_t)iv.y * 512 + c);
  o.x += wv.y * bflo(u.x); o.y += wv.y * bfhi(u.x);
  o.z += wv.y * bflo(u.y); o.w += wv.y * bfhi(u.y);
  u = *(const uint2*)(Y + (size_t)iv.z * 512 + c);
  o.x += wv.z * bflo(u.x); o.y += wv.z * bfhi(u.x);
  o.z += wv.z * bflo(u.y); o.w += wv.z * bfhi(u.y);
  u = *(const uint2*)(Y + (size_t)iv.w * 512 + c);
  o.x += wv.w * bflo(u.x); o.y += wv.w * bfhi(u.x);
  o.z += wv.w * bflo(u.y); o.w += wv.w * bfhi(u.y);
  *(float4*)op = o;
}

// ------------------------------------------------------------------ host ----
extern "C" void kernel_launch(void* const* d_in, const int* in_sizes, int n_in,
                              void* d_out, int out_size, void* d_ws, size_t ws_size,
                              hipStream_t stream) {
  const float* x   = (const float*)d_in[0];
  const float* gw  = (const float*)d_in[1];
  const float* gb  = (const float*)d_in[2];
  const float* w1  = (const float*)d_in[3];
  const float* b1  = (const float*)d_in[4];
  const float* w3  = (const float*)d_in[5];
  const float* b3  = (const float*)d_in[6];
  const float* w2  = (const float*)d_in[7];
  const float* b2  = (const float*)d_in[8];
  const float* sw1 = (const float*)d_in[9];
  const float* sb1 = (const float*)d_in[10];
  const float* sw3 = (const float*)d_in[11];
  const float* sb3 = (const float*)d_in[12];
  const float* sw2 = (const float*)d_in[13];
  const float* sb2 = (const float*)d_in[14];
  float* out = (float*)d_out;
  char* ws = (char*)d_ws;

  const size_t OFF_XB   = 134217728;
  const size_t OFF_W13I = 201326592;
  const size_t OFF_W2I  = 268435456;
  const size_t OFF_S13I = 301989888;
  const size_t OFF_SW2I = 306184192;
  const size_t OFF_IDX  = 308281344;
  const size_t OFF_WTS  = 308805632;
  const size_t OFF_TOK  = 309329920;
  const size_t OFF_INV  = 309854208;
  const size_t OFF_META = 310378496;
  if (ws_size < OFF_META + 8960) return;

  unsigned short* H    = (unsigned short*)ws;
  unsigned short* xb   = (unsigned short*)(ws + OFF_XB);
  unsigned short* Yb   = (unsigned short*)(ws + OFF_XB);
  unsigned short* w13i = (unsigned short*)(ws + OFF_W13I);
  unsigned short* w2i  = (unsigned short*)(ws + OFF_W2I);
  unsigned short* s13i = (unsigned short*)(ws + OFF_S13I);
  unsigned short* sw2i = (unsigned short*)(ws + OFF_SW2I);
  int*   idx  = (int*)(ws + OFF_IDX);
  float* wts  = (float*)(ws + OFF_WTS);
  int*   tokl = (int*)(ws + OFF_TOK);
  int*   inv  = (int*)(ws + OFF_INV);
  int*   meta = (int*)(ws + OFF_META);

  hipMemsetAsync(meta, 0, 128, stream);
  gate_kernel<<<dim3(8192), dim3(256), 0, stream>>>(x, gw, gb, idx, wts, xb);
  count_kernel<<<dim3(512), dim3(256), 0, stream>>>(idx, meta);
  scan_kernel<<<dim3(1), dim3(64), 0, stream>>>(meta);
  scatter_kernel<<<dim3(512), dim3(256), 0, stream>>>(idx, meta, tokl, inv);
  repack13_kernel<<<dim3(4096), dim3(256), 0, stream>>>(w1, w3, w13i, 1024, 512, 16);
  repack_kernel<<<dim3(2048), dim3(256), 0, stream>>>(w2, w2i, 512, 1024, 256);
  repack13_kernel<<<dim3(256), dim3(256), 0, stream>>>(sw1, sw3, s13i, 1024, 1024, 32);
  repack_kernel<<<dim3(128), dim3(256), 0, stream>>>(sw2, sw2i, 1024, 1024, 512);
  s1_kernel<<<dim3(1024), dim3(512), 0, stream>>>(xb, s13i, sb1, sb3, H);
  s2_kernel<<<dim3(512), dim3(512), 0, stream>>>(H, sw2i, sb2, out);
  g1_kernel<<<dim3(2176), dim3(512), 0, stream>>>(xb, w13i, b1, b3, tokl, meta, H);
  g2_kernel<<<dim3(1088), dim3(512), 0, stream>>>(H, w2i, b2, meta, Yb, 0);
  combine_kernel<<<dim3(16384), dim3(256), 0, stream>>>(Yb, inv, wts, out, 0);
  g2_kernel<<<dim3(1088), dim3(512), 0, stream>>>(H, w2i, b2, meta, Yb, 512);
  combine_kernel<<<dim3(16384), dim3(256), 0, stream>>>(Yb, inv, wts, out, 512);
}

// Round 9
// 1566.213 us; speedup vs baseline: 1.1029x; 1.0168x over previous
//
#include <hip/hip_runtime.h>
#include <stdint.h>

#define DIM_    1024
#define INTER_  512

typedef short bf16x4 __attribute__((ext_vector_type(4)));
typedef short bf16x8 __attribute__((ext_vector_type(8)));
typedef float f32x4  __attribute__((ext_vector_type(4)));

__device__ __forceinline__ unsigned short f2bf(float f) {
  union { float f; unsigned u; } v; v.f = f;
  return (unsigned short)((v.u + 0x7FFFu + ((v.u >> 16) & 1u)) >> 16);
}
__device__ __forceinline__ unsigned f2bf2(float a, float b) {
  union { float f; unsigned u; } va, vb; va.f = a; vb.f = b;
  unsigned ra = (va.u + 0x7FFFu + ((va.u >> 16) & 1u)) >> 16;
  unsigned rb = (vb.u + 0x7FFFu + ((vb.u >> 16) & 1u)) >> 16;
  return ra | (rb << 16);
}
__device__ __forceinline__ float bfhi(unsigned u) {
  union { unsigned u; float f; } v; v.u = u & 0xffff0000u; return v.f;
}
__device__ __forceinline__ float bflo(unsigned u) {
  union { unsigned u; float f; } v; v.u = u << 16; return v.f;
}

__device__ __forceinline__ void gl16(const void* g, void* l) {
  __builtin_amdgcn_global_load_lds(
      (const __attribute__((address_space(1))) unsigned int*)g,
      (__attribute__((address_space(3))) unsigned int*)l, 16, 0, 0);
}

#define BARX() do { asm volatile("" ::: "memory"); \
                    __builtin_amdgcn_s_barrier();  \
                    asm volatile("" ::: "memory"); } while (0)

// ---------------------------------------------------------------- gate ----
__global__ __launch_bounds__(256) void gate_kernel(
    const float* __restrict__ x, const float* __restrict__ gw,
    const float* __restrict__ gb, int* __restrict__ idx, float* __restrict__ wts,
    unsigned short* __restrict__ xb) {
  __shared__ double s_sc[4][32];
  __shared__ double s_gs[4][8];
  const int wid = threadIdx.x >> 6, lane = threadIdx.x & 63;
  const int t = blockIdx.x * 4 + wid;
  {
    const float* xrow = x + (size_t)t * DIM_ + lane * 16;
    unsigned short* xbrow = xb + (size_t)t * DIM_ + lane * 16;
    float4 f0 = *(const float4*)(xrow);
    float4 f1 = *(const float4*)(xrow + 4);
    float4 f2v = *(const float4*)(xrow + 8);
    float4 f3v = *(const float4*)(xrow + 12);
    uint4 o0, o1;
    o0.x = f2bf2(f0.x, f0.y);  o0.y = f2bf2(f0.z, f0.w);
    o0.z = f2bf2(f1.x, f1.y);  o0.w = f2bf2(f1.z, f1.w);
    o1.x = f2bf2(f2v.x, f2v.y); o1.y = f2bf2(f2v.z, f2v.w);
    o1.z = f2bf2(f3v.x, f3v.y); o1.w = f2bf2(f3v.z, f3v.w);
    *(uint4*)(xbrow) = o0;
    *(uint4*)(xbrow + 8) = o1;
  }
  const int e = lane & 31, half = lane >> 5;
  const float* xr  = x  + (size_t)t * DIM_ + half * 512;
  const float* gwp = gw + (size_t)half * 512 * 32 + e;
  double a0 = 0, a1 = 0, a2 = 0, a3 = 0;
  for (int k = 0; k < 512; k += 4) {
    float4 xv = *(const float4*)(xr + k);
    a0 += (double)xv.x * (double)gwp[(k + 0) * 32];
    a1 += (double)xv.y * (double)gwp[(k + 1) * 32];
    a2 += (double)xv.z * (double)gwp[(k + 2) * 32];
    a3 += (double)xv.w * (double)gwp[(k + 3) * 32];
  }
  double lg = (a0 + a1) + (a2 + a3);
  lg += __shfl_xor(lg, 32);
  lg += (double)gb[e];
  double m = lg;
  #pragma unroll
  for (int d = 1; d < 32; d <<= 1) m = fmax(m, __shfl_xor(m, d));
  double ex = exp(lg - m);
  double ssum = ex;
  #pragma unroll
  for (int d = 1; d < 32; d <<= 1) ssum += __shfl_xor(ssum, d);
  double sc = ex / ssum;
  double p  = __shfl_xor(sc, 1);
  double m1 = fmax(sc, p), n1 = fmin(sc, p);
  double m2 = __shfl_xor(m1, 2), n2 = __shfl_xor(n1, 2);
  double gs = (m1 >= m2) ? (m1 + fmax(n1, m2)) : (m2 + fmax(n2, m1));
  if (lane < 32) {
    s_sc[wid][e] = sc;
    if ((e & 3) == 0) s_gs[wid][e >> 2] = gs;
  }
  __syncthreads();
  if (lane == 0) {
    unsigned kmask = 0;
    for (int it = 0; it < 4; ++it) {
      int bg = 0; double bv = -1.0;
      for (int g = 0; g < 8; ++g)
        if (!((kmask >> g) & 1u) && s_gs[wid][g] > bv) { bv = s_gs[wid][g]; bg = g; }
      kmask |= 1u << bg;
    }
    unsigned umask = 0;
    for (int slot = 0; slot < 4; ++slot) {
      int be = 0; double bv = -1.0;
      for (int ee = 0; ee < 32; ++ee)
        if (((kmask >> (ee >> 2)) & 1u) && !((umask >> ee) & 1u) && s_sc[wid][ee] > bv) {
          bv = s_sc[wid][ee]; be = ee;
        }
      umask |= 1u << be;
      idx[t * 4 + slot] = be;
      wts[t * 4 + slot] = (float)bv;
    }
  }
}

// ------------------------------------------------- dispatch bookkeeping ----
__global__ __launch_bounds__(256) void count_kernel(const int* __restrict__ idx,
                                                    int* __restrict__ meta) {
  __shared__ int h[32];
  int tid = threadIdx.x;
  if (tid < 32) h[tid] = 0;
  __syncthreads();
  atomicAdd(&h[idx[blockIdx.x * 256 + tid]], 1);
  __syncthreads();
  if (tid < 32 && h[tid]) atomicAdd(&meta[tid], h[tid]);
}

__global__ void scan_kernel(int* __restrict__ meta) {
  int lane = threadIdx.x & 63;
  if (lane < 32) {
    int c = meta[lane];
    int pre = c;
    #pragma unroll
    for (int d = 1; d < 32; d <<= 1) { int t = __shfl_up(pre, d); if (lane >= d) pre += t; }
    int excl = pre - c;
    meta[64 + lane] = excl;
    meta[32 + lane] = excl;
    int nt = (c + 255) >> 8;
    int ntp = nt;
    #pragma unroll
    for (int d = 1; d < 32; d <<= 1) { int t = __shfl_up(ntp, d); if (lane >= d) ntp += t; }
    int ntExcl = ntp - nt;
    for (int k = 0; k < nt; ++k) { meta[128 + ntExcl + k] = lane; meta[1184 + ntExcl + k] = k << 8; }
    if (lane == 31) { meta[96] = excl + c; meta[97] = ntExcl + nt; }
  }
}

__global__ __launch_bounds__(256) void scatter_kernel(
    const int* __restrict__ idx, int* __restrict__ meta,
    int* __restrict__ tok, int* __restrict__ inv) {
  int i = blockIdx.x * 256 + threadIdx.x;
  int lane = threadIdx.x & 63;
  int e = idx[i];
  unsigned long long m = ~0ull;
  #pragma unroll
  for (int b = 0; b < 5; ++b) {
    unsigned long long vote = __ballot((e >> b) & 1);
    m &= ((e >> b) & 1) ? vote : ~vote;
  }
  int leader = __ffsll((long long)m) - 1;
  int rank = __popcll(m & ((1ull << lane) - 1));
  int base = 0;
  if (lane == leader) base = atomicAdd(&meta[32 + e], (int)__popcll(m));
  base = __shfl(base, leader);
  int p = base + rank;
  tok[p] = i >> 2;
  inv[i] = p;
}

// ----------------------------------------------------------- repacking ----
__global__ __launch_bounds__(256) void repack_kernel(
    const float* __restrict__ src, unsigned short* __restrict__ dst,
    int K, int N, int tilesPerMat) {
  const int w = blockIdx.x * 4 + (threadIdx.x >> 6);
  const int j = threadIdx.x & 63;
  const int e = w / tilesPerMat, rem = w % tilesPerMat;
  const int kSteps = K >> 5;
  const int nt = rem / kSteps, kq = rem % kSteps;
  const float* s = src + (size_t)e * K * N + (size_t)(kq * 32) * N + nt * 64 + j;
  float v[32];
  #pragma unroll
  for (int kk = 0; kk < 32; ++kk) v[kk] = s[(size_t)kk * N];
  char* d = (char*)dst + (size_t)w * 4096 + j * 64;
  const int sz = (j & 3) ^ ((j >> 2) & 3);
  #pragma unroll
  for (int q = 0; q < 4; ++q) {
    int o = (q ^ sz) * 8;
    uint4 tv;
    tv.x = f2bf2(v[o + 0], v[o + 1]);
    tv.y = f2bf2(v[o + 2], v[o + 3]);
    tv.z = f2bf2(v[o + 4], v[o + 5]);
    tv.w = f2bf2(v[o + 6], v[o + 7]);
    *(uint4*)(d + q * 16) = tv;
  }
}

__global__ __launch_bounds__(256) void repack13_kernel(
    const float* __restrict__ src1, const float* __restrict__ src3,
    unsigned short* __restrict__ dst, int K, int N, int jtTiles) {
  const int w = blockIdx.x * 4 + (threadIdx.x >> 6);
  const int j = threadIdx.x & 63;
  const int kSteps = K >> 5;
  const int tpm = jtTiles * kSteps;
  const int e = w / tpm, rem = w % tpm;
  const int jt = rem / kSteps, kq = rem % kSteps;
  const int jg = jt * 64 + j;
  const int c = ((jg >> 5) << 4) + (jg & 15);
  const float* s = (((jg >> 4) & 1) ? src3 : src1)
                 + (size_t)e * K * N + (size_t)(kq * 32) * N + c;
  float v[32];
  #pragma unroll
  for (int kk = 0; kk < 32; ++kk) v[kk] = s[(size_t)kk * N];
  char* d = (char*)dst + (size_t)w * 4096 + j * 64;
  const int sz = (j & 3) ^ ((j >> 2) & 3);
  #pragma unroll
  for (int q = 0; q < 4; ++q) {
    int o = (q ^ sz) * 8;
    uint4 tv;
    tv.x = f2bf2(v[o + 0], v[o + 1]);
    tv.y = f2bf2(v[o + 2], v[o + 3]);
    tv.z = f2bf2(v[o + 4], v[o + 5]);
    tv.w = f2bf2(v[o + 6], v[o + 7]);
    *(uint4*)(d + q * 16) = tv;
  }
}

// ===== 256x256 8-phase GEMM core, reg-double-buffered frag pipeline ========
// One barrier per phase. Even phase 2s: stage unit I4+3+s (4 gl16) into slot
// (s+3)&3; early-read odd-half A of slot s into AFN; MFMA(AFC, BVC) -> acc[0..3];
// vmcnt(4) (validates slot s+1 for next phase's early reads).
// Odd phase 2s+1: early-read next unit's even-A + B from slot (s+1)&3;
// MFMA(af1, BVC) -> acc[4..7]. All frag reads overlap the MFMA cluster of the
// same phase (consumed next phase; compiler inserts the lgkmcnt there).

#define G8_PRE()                                                              \
  const int tid = threadIdx.x, lane = tid & 63, wave = tid >> 6;              \
  const int wm = wave >> 2, wn = wave & 3;                                    \
  const int f = lane & 15, g = lane >> 4;                                     \
  const int wud = wave >> 2, wlo = wave & 3;                                  \
  const int row_in = wlo * 16 + (lane >> 2);                                  \
  const int szr = (row_in & 3) ^ ((row_in >> 2) & 3);                         \
  const int qs = (((lane & 3) ^ szr) << 4);                                   \
  const int btile_off = wlo * 1024 + lane * 16;                               \
  const int wv1k = wave * 1024;                                               \
  const int awb = wm * 8192;                                                  \
  const int wn4 = wn * 4096;                                                  \
  int aoff[4];                                                                \
  _Pragma("unroll")                                                           \
  for (int ii = 0; ii < 4; ++ii) {                                            \
    int u16 = ii * 16 + f;                                                    \
    aoff[ii] = u16 * 64 + ((g ^ ((u16 & 3) ^ ((u16 >> 2) & 3))) << 4);        \
  }                                                                           \
  f32x4 acc[8][4];                                                            \
  const f32x4 zz = {0.f, 0.f, 0.f, 0.f};                                      \
  _Pragma("unroll")                                                           \
  for (int mi = 0; mi < 8; ++mi)                                              \
    _Pragma("unroll")                                                         \
    for (int ni = 0; ni < 4; ++ni) acc[mi][ni] = zz;

#define G8_EVEN(s, AFC, AFN, BVC, UMAXv)                                      \
  {                                                                           \
    BARX();                                                                   \
    int u_ = I4 + 3 + (s); if (u_ >= (UMAXv)) u_ = (UMAXv) - 1;               \
    char* td_ = lds + ((((s) + 3) & 3) * 32768);                              \
    gl16(pA0 + u_ * 64, td_ + wv1k);                                          \
    gl16(pA1 + u_ * 64, td_ + 8192 + wv1k);                                   \
    gl16(pB0 + (size_t)u_ * 4096, td_ + 16384 + wv1k);                        \
    gl16(pB1 + (size_t)u_ * 4096, td_ + 24576 + wv1k);                        \
    const char* cb_ = lds + (((s) & 3) * 32768);                              \
    _Pragma("unroll")                                                         \
    for (int mi = 0; mi < 4; ++mi)                                            \
      AFN[mi] = *(const bf16x8*)(cb_ + awb + 4096 + aoff[mi]);                \
    __builtin_amdgcn_s_setprio(1);                                            \
    _Pragma("unroll")                                                         \
    for (int ni = 0; ni < 4; ++ni)                                            \
      _Pragma("unroll")                                                       \
      for (int mi = 0; mi < 4; ++mi)                                          \
        acc[mi][ni] = __builtin_amdgcn_mfma_f32_16x16x32_bf16(                \
            AFC[mi], BVC[ni], acc[mi][ni], 0, 0, 0);                          \
    __builtin_amdgcn_s_setprio(0);                                            \
    asm volatile("s_waitcnt vmcnt(4)" ::: "memory");                          \
  }

#define G8_ODD(s, AFC, BVC, AFN, BVN)                                         \
  {                                                                           \
    BARX();                                                                   \
    const char* nb_ = lds + ((((s) + 1) & 3) * 32768);                        \
    _Pragma("unroll")                                                         \
    for (int mi = 0; mi < 4; ++mi)                                            \
      AFN[mi] = *(const bf16x8*)(nb_ + awb + aoff[mi]);                       \
    _Pragma("unroll")                                                         \
    for (int ni = 0; ni < 4; ++ni)                                            \
      BVN[ni] = *(const bf16x8*)(nb_ + 16384 + wn4 + aoff[ni]);               \
    __builtin_amdgcn_s_setprio(1);                                            \
    _Pragma("unroll")                                                         \
    for (int ni = 0; ni < 4; ++ni)                                            \
      _Pragma("unroll")                                                       \
      for (int mi = 0; mi < 4; ++mi)                                          \
        acc[4 + mi][ni] = __builtin_amdgcn_mfma_f32_16x16x32_bf16(            \
            AFC[mi], BVC[ni], acc[4 + mi][ni], 0, 0, 0);                      \
    __builtin_amdgcn_s_setprio(0);                                            \
  }

#define G8_BODY(UMAXv)                                                        \
  _Pragma("unroll")                                                           \
  for (int uu = 0; uu < 3; ++uu) {                                            \
    gl16(pA0 + uu * 64, lds + uu * 32768 + wv1k);                             \
    gl16(pA1 + uu * 64, lds + uu * 32768 + 8192 + wv1k);                      \
    gl16(pB0 + (size_t)uu * 4096, lds + uu * 32768 + 16384 + wv1k);           \
    gl16(pB1 + (size_t)uu * 4096, lds + uu * 32768 + 24576 + wv1k);           \
  }                                                                           \
  asm volatile("s_waitcnt vmcnt(8)" ::: "memory");                            \
  BARX();                                                                     \
  bf16x8 af0[4], af1[4], bv0[4], bv1[4];                                      \
  _Pragma("unroll")                                                           \
  for (int mi = 0; mi < 4; ++mi)                                              \
    af0[mi] = *(const bf16x8*)(lds + awb + aoff[mi]);                         \
  _Pragma("unroll")                                                           \
  for (int ni = 0; ni < 4; ++ni)                                              \
    bv0[ni] = *(const bf16x8*)(lds + 16384 + wn4 + aoff[ni]);                 \
  for (int I = 0; I < (UMAXv) / 4; ++I) {                                     \
    const int I4 = I * 4;                                                     \
    G8_EVEN(0, af0, af1, bv0, UMAXv); G8_ODD(0, af1, bv0, af0, bv1);          \
    G8_EVEN(1, af0, af1, bv1, UMAXv); G8_ODD(1, af1, bv1, af0, bv0);          \
    G8_EVEN(2, af0, af1, bv0, UMAXv); G8_ODD(2, af1, bv0, af0, bv1);          \
    G8_EVEN(3, af0, af1, bv1, UMAXv); G8_ODD(3, af1, bv1, af0, bv0);          \
  }

// XCD-chunked flat swizzle: consecutive work-ids land on the same XCD.
#define XCD_SWZ(GXv)                                                          \
  const int nb_ = gridDim.x;                                                  \
  const int b_ = blockIdx.x;                                                  \
  const int w_ = (b_ & 7) * (nb_ >> 3) + (b_ >> 3);                           \
  const int bx = w_ % (GXv);                                                  \
  const int by = w_ / (GXv);

// --------------------------------------------------------- shared GEMM1 ----
__global__ __launch_bounds__(512, 2) void s1_kernel(
    const unsigned short* __restrict__ xb, const unsigned short* __restrict__ w13,
    const float* __restrict__ sb1, const float* __restrict__ sb3,
    unsigned short* __restrict__ Hs) {
  __shared__ char lds[131072];
  XCD_SWZ(8);
  const int m0 = by * 256;
  G8_PRE();
  const char* pA0 = (const char*)xb + (size_t)(m0 + wud * 64 + row_in) * 2048 + qs;
  const char* pA1 = pA0 + (size_t)128 * 2048;
  const char* pB0 = (const char*)w13 + ((size_t)(bx * 4 + wud) * 32) * 4096 + btile_off;
  const char* pB1 = (const char*)w13 + ((size_t)(bx * 4 + 2 + wud) * 32) * 4096 + btile_off;
  G8_BODY(32);
  const int colb = bx * 128;
  #pragma unroll
  for (int p2 = 0; p2 < 2; ++p2) {
    int c = colb + wn * 32 + p2 * 16 + f;
    float bb1 = sb1[c], bb3 = sb3[c];
    #pragma unroll
    for (int m8 = 0; m8 < 8; ++m8) {
      int row = m0 + wm * 128 + (m8 >> 2) * 64 + (m8 & 3) * 16 + g * 4;
      #pragma unroll
      for (int r = 0; r < 4; ++r) {
        float v1 = acc[m8][2 * p2][r] + bb1;
        float v3 = acc[m8][2 * p2 + 1][r] + bb3;
        float h = (v1 / (1.f + __expf(-v1))) * v3;
        Hs[(size_t)(row + r) * 1024 + c] = f2bf(h);
      }
    }
  }
}

// --------------------------------------------------------- shared GEMM2 ----
__global__ __launch_bounds__(512, 2) void s2_kernel(
    const unsigned short* __restrict__ Hs, const unsigned short* __restrict__ b2i,
    const float* __restrict__ sb2, float* __restrict__ out) {
  __shared__ char lds[131072];
  XCD_SWZ(4);
  const int m0 = by * 256;
  G8_PRE();
  const char* pA0 = (const char*)Hs + (size_t)(m0 + wud * 64 + row_in) * 2048 + qs;
  const char* pA1 = pA0 + (size_t)128 * 2048;
  const char* pB0 = (const char*)b2i + ((size_t)(bx * 4 + wud) * 32) * 4096 + btile_off;
  const char* pB1 = (const char*)b2i + ((size_t)(bx * 4 + 2 + wud) * 32) * 4096 + btile_off;
  G8_BODY(32);
  #pragma unroll
  for (int ni = 0; ni < 4; ++ni) {
    int c = bx * 256 + wn * 64 + ni * 16 + f;
    float bb = sb2[c];
    #pragma unroll
    for (int m8 = 0; m8 < 8; ++m8) {
      int row = m0 + wm * 128 + (m8 >> 2) * 64 + (m8 & 3) * 16 + g * 4;
      #pragma unroll
      for (int r = 0; r < 4; ++r)
        out[(size_t)(row + r) * 1024 + c] = acc[m8][ni][r] + bb;
    }
  }
}

// --------------------------------------------------------- routed GEMM1 ----
__global__ __launch_bounds__(512, 2) void g1_kernel(
    const unsigned short* __restrict__ xb, const unsigned short* __restrict__ w13,
    const float* __restrict__ b1, const float* __restrict__ b3,
    const int* __restrict__ tok, const int* __restrict__ meta,
    unsigned short* __restrict__ H) {
  __shared__ char lds[131072];
  XCD_SWZ(4);
  if (by >= meta[97]) return;
  const int e = meta[128 + by], m0 = meta[1184 + by];
  const int off_e = meta[64 + e], nrem = meta[e] - m0;
  G8_PRE();
  const int r0a = wud * 64 + row_in;
  const int ix0 = off_e + m0 + ((r0a < nrem) ? r0a : 0);
  const int ix1 = off_e + m0 + ((r0a + 128 < nrem) ? r0a + 128 : 0);
  const char* pA0 = (const char*)xb + (size_t)tok[ix0] * 2048 + qs;
  const char* pA1 = (const char*)xb + (size_t)tok[ix1] * 2048 + qs;
  const char* pB0 = (const char*)w13 + ((size_t)(e * 16 + bx * 4 + wud) * 32) * 4096 + btile_off;
  const char* pB1 = (const char*)w13 + ((size_t)(e * 16 + bx * 4 + 2 + wud) * 32) * 4096 + btile_off;
  G8_BODY(32);
  const int colb = bx * 128;
  #pragma unroll
  for (int p2 = 0; p2 < 2; ++p2) {
    int c = colb + wn * 32 + p2 * 16 + f;
    float bb1 = b1[e * 512 + c], bb3 = b3[e * 512 + c];
    #pragma unroll
    for (int m8 = 0; m8 < 8; ++m8) {
      int row = wm * 128 + (m8 >> 2) * 64 + (m8 & 3) * 16 + g * 4;
      #pragma unroll
      for (int r = 0; r < 4; ++r) {
        if (row + r < nrem) {
          float v1 = acc[m8][2 * p2][r] + bb1;
          float v3 = acc[m8][2 * p2 + 1][r] + bb3;
          float h = (v1 / (1.f + __expf(-v1))) * v3;
          H[(size_t)(off_e + m0 + row + r) * 512 + c] = f2bf(h);
        }
      }
    }
  }
}

// --------------------------------------------------------- routed GEMM2 ----
__global__ __launch_bounds__(512, 2) void g2_kernel(
    const unsigned short* __restrict__ H, const unsigned short* __restrict__ w2i,
    const float* __restrict__ b2, const int* __restrict__ meta,
    unsigned short* __restrict__ Y, int cbase) {
  __shared__ char lds[131072];
  XCD_SWZ(2);
  if (by >= meta[97]) return;
  const int e = meta[128 + by], m0 = meta[1184 + by];
  const int off_e = meta[64 + e], nrem = meta[e] - m0;
  G8_PRE();
  const int r0a = wud * 64 + row_in;
  const int ix0 = off_e + m0 + ((r0a < nrem) ? r0a : 0);
  const int ix1 = off_e + m0 + ((r0a + 128 < nrem) ? r0a + 128 : 0);
  const char* pA0 = (const char*)H + (size_t)ix0 * 1024 + qs;
  const char* pA1 = (const char*)H + (size_t)ix1 * 1024 + qs;
  const int nt0 = (cbase >> 6) + bx * 4;
  const char* pB0 = (const char*)w2i + ((size_t)(e * 16 + nt0 + wud) * 16) * 4096 + btile_off;
  const char* pB1 = (const char*)w2i + ((size_t)(e * 16 + nt0 + 2 + wud) * 16) * 4096 + btile_off;
  G8_BODY(16);
  #pragma unroll
  for (int ni = 0; ni < 4; ++ni) {
    int ycol = bx * 256 + wn * 64 + ni * 16 + f;
    float bb = b2[e * 1024 + cbase + ycol];
    #pragma unroll
    for (int m8 = 0; m8 < 8; ++m8) {
      int row = wm * 128 + (m8 >> 2) * 64 + (m8 & 3) * 16 + g * 4;
      #pragma unroll
      for (int r = 0; r < 4; ++r) {
        if (row + r < nrem)
          Y[(size_t)(off_e + m0 + row + r) * 512 + ycol] = f2bf(acc[m8][ni][r] + bb);
      }
    }
  }
}

// ------------------------------------------------------------- combine ----
__global__ __launch_bounds__(256) void combine_kernel(
    const unsigned short* __restrict__ Y, const int* __restrict__ inv,
    const float* __restrict__ wts, float* __restrict__ out, int cbase) {
  int t = blockIdx.x * 2 + (threadIdx.x >> 7);
  int c = (threadIdx.x & 127) * 4;
  int4 iv = *(const int4*)(inv + t * 4);
  float4 wv = *(const float4*)(wts + t * 4);
  float* op = out + (size_t)t * 1024 + cbase + c;
  float4 o = *(float4*)op;
  uint2 u;
  u = *(const uint2*)(Y + (size_t)iv.x * 512 + c);
  o.x += wv.x * bflo(u.x); o.y += wv.x * bfhi(u.x);
  o.z += wv.x * bflo(u.y); o.w += wv.x * bfhi(u.y);
  u = *(const uint2*)(Y + (size_t)iv.y * 512 + c);
  o.x += wv.y * bflo(u.x); o.y += wv.y * bfhi(u.x);
  o.z += wv.y * bflo(u.y); o.w += wv.y * bfhi(u.y);
  u = *(const uint2*)(Y + (size_t)iv.z * 512 + c);
  o.x += wv.z * bflo(u.x); o.y += wv.z * bfhi(u.x);
  o.z += wv.z * bflo(u.y); o.w += wv.z * bfhi(u.y);
  u = *(const uint2*)(Y + (size_t)iv.w * 512 + c);
  o.x += wv.w * bflo(u.x); o.y += wv.w * bfhi(u.x);
  o.z += wv.w * bflo(u.y); o.w += wv.w * bfhi(u.y);
  *(float4*)op = o;
}

// ------------------------------------------------------------------ host ----
extern "C" void kernel_launch(void* const* d_in, const int* in_sizes, int n_in,
                              void* d_out, int out_size, void* d_ws, size_t ws_size,
                              hipStream_t stream) {
  const float* x   = (const float*)d_in[0];
  const float* gw  = (const float*)d_in[1];
  const float* gb  = (const float*)d_in[2];
  const float* w1  = (const float*)d_in[3];
  const float* b1  = (const float*)d_in[4];
  const float* w3  = (const float*)d_in[5];
  const float* b3  = (const float*)d_in[6];
  const float* w2  = (const float*)d_in[7];
  const float* b2  = (const float*)d_in[8];
  const float* sw1 = (const float*)d_in[9];
  const float* sb1 = (const float*)d_in[10];
  const float* sw3 = (const float*)d_in[11];
  const float* sb3 = (const float*)d_in[12];
  const float* sw2 = (const float*)d_in[13];
  const float* sb2 = (const float*)d_in[14];
  float* out = (float*)d_out;
  char* ws = (char*)d_ws;

  const size_t OFF_XB   = 134217728;
  const size_t OFF_W13I = 201326592;
  const size_t OFF_W2I  = 268435456;
  const size_t OFF_S13I = 301989888;
  const size_t OFF_SW2I = 306184192;
  const size_t OFF_IDX  = 308281344;
  const size_t OFF_WTS  = 308805632;
  const size_t OFF_TOK  = 309329920;
  const size_t OFF_INV  = 309854208;
  const size_t OFF_META = 310378496;
  if (ws_size < OFF_META + 8960) return;

  unsigned short* H    = (unsigned short*)ws;
  unsigned short* xb   = (unsigned short*)(ws + OFF_XB);
  unsigned short* Yb   = (unsigned short*)(ws + OFF_XB);
  unsigned short* w13i = (unsigned short*)(ws + OFF_W13I);
  unsigned short* w2i  = (unsigned short*)(ws + OFF_W2I);
  unsigned short* s13i = (unsigned short*)(ws + OFF_S13I);
  unsigned short* sw2i = (unsigned short*)(ws + OFF_SW2I);
  int*   idx  = (int*)(ws + OFF_IDX);
  float* wts  = (float*)(ws + OFF_WTS);
  int*   tokl = (int*)(ws + OFF_TOK);
  int*   inv  = (int*)(ws + OFF_INV);
  int*   meta = (int*)(ws + OFF_META);

  hipMemsetAsync(meta, 0, 128, stream);
  gate_kernel<<<dim3(8192), dim3(256), 0, stream>>>(x, gw, gb, idx, wts, xb);
  count_kernel<<<dim3(512), dim3(256), 0, stream>>>(idx, meta);
  scan_kernel<<<dim3(1), dim3(64), 0, stream>>>(meta);
  scatter_kernel<<<dim3(512), dim3(256), 0, stream>>>(idx, meta, tokl, inv);
  repack13_kernel<<<dim3(4096), dim3(256), 0, stream>>>(w1, w3, w13i, 1024, 512, 16);
  repack_kernel<<<dim3(2048), dim3(256), 0, stream>>>(w2, w2i, 512, 1024, 256);
  repack13_kernel<<<dim3(256), dim3(256), 0, stream>>>(sw1, sw3, s13i, 1024, 1024, 32);
  repack_kernel<<<dim3(128), dim3(256), 0, stream>>>(sw2, sw2i, 1024, 1024, 512);
  s1_kernel<<<dim3(1024), dim3(512), 0, stream>>>(xb, s13i, sb1, sb3, H);
  s2_kernel<<<dim3(512), dim3(512), 0, stream>>>(H, sw2i, sb2, out);
  g1_kernel<<<dim3(2176), dim3(512), 0, stream>>>(xb, w13i, b1, b3, tokl, meta, H);
  g2_kernel<<<dim3(1088), dim3(512), 0, stream>>>(H, w2i, b2, meta, Yb, 0);
  combine_kernel<<<dim3(16384), dim3(256), 0, stream>>>(Yb, inv, wts, out, 0);
  g2_kernel<<<dim3(1088), dim3(512), 0, stream>>>(H, w2i, b2, meta, Yb, 512);
  combine_kernel<<<dim3(16384), dim3(256), 0, stream>>>(Yb, inv, wts, out, 512);
}

// Round 10
// 1493.306 us; speedup vs baseline: 1.1568x; 1.0488x over previous
//
#include <hip/hip_runtime.h>
#include <stdint.h>

#define DIM_    1024
#define INTER_  512

typedef short bf16x4 __attribute__((ext_vector_type(4)));
typedef short bf16x8 __attribute__((ext_vector_type(8)));
typedef float f32x4  __attribute__((ext_vector_type(4)));

__device__ __forceinline__ unsigned short f2bf(float f) {
  union { float f; unsigned u; } v; v.f = f;
  return (unsigned short)((v.u + 0x7FFFu + ((v.u >> 16) & 1u)) >> 16);
}
__device__ __forceinline__ unsigned f2bf2(float a, float b) {
  union { float f; unsigned u; } va, vb; va.f = a; vb.f = b;
  unsigned ra = (va.u + 0x7FFFu + ((va.u >> 16) & 1u)) >> 16;
  unsigned rb = (vb.u + 0x7FFFu + ((vb.u >> 16) & 1u)) >> 16;
  return ra | (rb << 16);
}
__device__ __forceinline__ float bfhi(unsigned u) {
  union { unsigned u; float f; } v; v.u = u & 0xffff0000u; return v.f;
}
__device__ __forceinline__ float bflo(unsigned u) {
  union { unsigned u; float f; } v; v.u = u << 16; return v.f;
}

__device__ __forceinline__ void gl16(const void* g, void* l) {
  __builtin_amdgcn_global_load_lds(
      (const __attribute__((address_space(1))) unsigned int*)g,
      (__attribute__((address_space(3))) unsigned int*)l, 16, 0, 0);
}

#define BARX() do { asm volatile("" ::: "memory"); \
                    __builtin_amdgcn_s_barrier();  \
                    asm volatile("" ::: "memory"); } while (0)

// ---------------------------------------------------------------- gate ----
__global__ __launch_bounds__(256) void gate_kernel(
    const float* __restrict__ x, const float* __restrict__ gw,
    const float* __restrict__ gb, int* __restrict__ idx, float* __restrict__ wts,
    unsigned short* __restrict__ xb) {
  __shared__ double s_sc[4][32];
  __shared__ double s_gs[4][8];
  const int wid = threadIdx.x >> 6, lane = threadIdx.x & 63;
  const int t = blockIdx.x * 4 + wid;
  {
    const float* xrow = x + (size_t)t * DIM_ + lane * 16;
    unsigned short* xbrow = xb + (size_t)t * DIM_ + lane * 16;
    float4 f0 = *(const float4*)(xrow);
    float4 f1 = *(const float4*)(xrow + 4);
    float4 f2v = *(const float4*)(xrow + 8);
    float4 f3v = *(const float4*)(xrow + 12);
    uint4 o0, o1;
    o0.x = f2bf2(f0.x, f0.y);  o0.y = f2bf2(f0.z, f0.w);
    o0.z = f2bf2(f1.x, f1.y);  o0.w = f2bf2(f1.z, f1.w);
    o1.x = f2bf2(f2v.x, f2v.y); o1.y = f2bf2(f2v.z, f2v.w);
    o1.z = f2bf2(f3v.x, f3v.y); o1.w = f2bf2(f3v.z, f3v.w);
    *(uint4*)(xbrow) = o0;
    *(uint4*)(xbrow + 8) = o1;
  }
  const int e = lane & 31, half = lane >> 5;
  const float* xr  = x  + (size_t)t * DIM_ + half * 512;
  const float* gwp = gw + (size_t)half * 512 * 32 + e;
  double a0 = 0, a1 = 0, a2 = 0, a3 = 0;
  for (int k = 0; k < 512; k += 4) {
    float4 xv = *(const float4*)(xr + k);
    a0 += (double)xv.x * (double)gwp[(k + 0) * 32];
    a1 += (double)xv.y * (double)gwp[(k + 1) * 32];
    a2 += (double)xv.z * (double)gwp[(k + 2) * 32];
    a3 += (double)xv.w * (double)gwp[(k + 3) * 32];
  }
  double lg = (a0 + a1) + (a2 + a3);
  lg += __shfl_xor(lg, 32);
  lg += (double)gb[e];
  double m = lg;
  #pragma unroll
  for (int d = 1; d < 32; d <<= 1) m = fmax(m, __shfl_xor(m, d));
  double ex = exp(lg - m);
  double ssum = ex;
  #pragma unroll
  for (int d = 1; d < 32; d <<= 1) ssum += __shfl_xor(ssum, d);
  double sc = ex / ssum;
  double p  = __shfl_xor(sc, 1);
  double m1 = fmax(sc, p), n1 = fmin(sc, p);
  double m2 = __shfl_xor(m1, 2), n2 = __shfl_xor(n1, 2);
  double gs = (m1 >= m2) ? (m1 + fmax(n1, m2)) : (m2 + fmax(n2, m1));
  if (lane < 32) {
    s_sc[wid][e] = sc;
    if ((e & 3) == 0) s_gs[wid][e >> 2] = gs;
  }
  __syncthreads();
  if (lane == 0) {
    unsigned kmask = 0;
    for (int it = 0; it < 4; ++it) {
      int bg = 0; double bv = -1.0;
      for (int g = 0; g < 8; ++g)
        if (!((kmask >> g) & 1u) && s_gs[wid][g] > bv) { bv = s_gs[wid][g]; bg = g; }
      kmask |= 1u << bg;
    }
    unsigned umask = 0;
    for (int slot = 0; slot < 4; ++slot) {
      int be = 0; double bv = -1.0;
      for (int ee = 0; ee < 32; ++ee)
        if (((kmask >> (ee >> 2)) & 1u) && !((umask >> ee) & 1u) && s_sc[wid][ee] > bv) {
          bv = s_sc[wid][ee]; be = ee;
        }
      umask |= 1u << be;
      idx[t * 4 + slot] = be;
      wts[t * 4 + slot] = (float)bv;
    }
  }
}

// ------------------------------------------------- dispatch bookkeeping ----
__global__ __launch_bounds__(256) void count_kernel(const int* __restrict__ idx,
                                                    int* __restrict__ meta) {
  __shared__ int h[32];
  int tid = threadIdx.x;
  if (tid < 32) h[tid] = 0;
  __syncthreads();
  atomicAdd(&h[idx[blockIdx.x * 256 + tid]], 1);
  __syncthreads();
  if (tid < 32 && h[tid]) atomicAdd(&meta[tid], h[tid]);
}

__global__ void scan_kernel(int* __restrict__ meta) {
  int lane = threadIdx.x & 63;
  if (lane < 32) {
    int c = meta[lane];
    int pre = c;
    #pragma unroll
    for (int d = 1; d < 32; d <<= 1) { int t = __shfl_up(pre, d); if (lane >= d) pre += t; }
    int excl = pre - c;
    meta[64 + lane] = excl;
    meta[32 + lane] = excl;
    int nt = (c + 255) >> 8;
    int ntp = nt;
    #pragma unroll
    for (int d = 1; d < 32; d <<= 1) { int t = __shfl_up(ntp, d); if (lane >= d) ntp += t; }
    int ntExcl = ntp - nt;
    for (int k = 0; k < nt; ++k) { meta[128 + ntExcl + k] = lane; meta[1184 + ntExcl + k] = k << 8; }
    if (lane == 31) { meta[96] = excl + c; meta[97] = ntExcl + nt; }
  }
}

__global__ __launch_bounds__(256) void scatter_kernel(
    const int* __restrict__ idx, int* __restrict__ meta,
    int* __restrict__ tok, int* __restrict__ inv) {
  int i = blockIdx.x * 256 + threadIdx.x;
  int lane = threadIdx.x & 63;
  int e = idx[i];
  unsigned long long m = ~0ull;
  #pragma unroll
  for (int b = 0; b < 5; ++b) {
    unsigned long long vote = __ballot((e >> b) & 1);
    m &= ((e >> b) & 1) ? vote : ~vote;
  }
  int leader = __ffsll((long long)m) - 1;
  int rank = __popcll(m & ((1ull << lane) - 1));
  int base = 0;
  if (lane == leader) base = atomicAdd(&meta[32 + e], (int)__popcll(m));
  base = __shfl(base, leader);
  int p = base + rank;
  tok[p] = i >> 2;
  inv[i] = p;
}

// ----------------------------------------------------------- repacking ----
// B-image tiles now OCTET-MAJOR: tile (64 cols x 32 k, 4KB) stores k-octet q
// of col j at q*1024 + j*16. Frag read = g*1024 + col*16 -> 16 lanes hit 256
// consecutive bytes = conflict-free ds_read_b128. No XOR swizzle needed.
__global__ __launch_bounds__(256) void repack_kernel(
    const float* __restrict__ src, unsigned short* __restrict__ dst,
    int K, int N, int tilesPerMat) {
  const int w = blockIdx.x * 4 + (threadIdx.x >> 6);
  const int j = threadIdx.x & 63;
  const int e = w / tilesPerMat, rem = w % tilesPerMat;
  const int kSteps = K >> 5;
  const int nt = rem / kSteps, kq = rem % kSteps;
  const float* s = src + (size_t)e * K * N + (size_t)(kq * 32) * N + nt * 64 + j;
  float v[32];
  #pragma unroll
  for (int kk = 0; kk < 32; ++kk) v[kk] = s[(size_t)kk * N];
  char* d = (char*)dst + (size_t)w * 4096 + j * 16;
  #pragma unroll
  for (int q = 0; q < 4; ++q) {
    int o = q * 8;
    uint4 tv;
    tv.x = f2bf2(v[o + 0], v[o + 1]);
    tv.y = f2bf2(v[o + 2], v[o + 3]);
    tv.z = f2bf2(v[o + 4], v[o + 5]);
    tv.w = f2bf2(v[o + 6], v[o + 7]);
    *(uint4*)(d + q * 1024) = tv;
  }
}

__global__ __launch_bounds__(256) void repack13_kernel(
    const float* __restrict__ src1, const float* __restrict__ src3,
    unsigned short* __restrict__ dst, int K, int N, int jtTiles) {
  const int w = blockIdx.x * 4 + (threadIdx.x >> 6);
  const int j = threadIdx.x & 63;
  const int kSteps = K >> 5;
  const int tpm = jtTiles * kSteps;
  const int e = w / tpm, rem = w % tpm;
  const int jt = rem / kSteps, kq = rem % kSteps;
  const int jg = jt * 64 + j;
  const int c = ((jg >> 5) << 4) + (jg & 15);
  const float* s = (((jg >> 4) & 1) ? src3 : src1)
                 + (size_t)e * K * N + (size_t)(kq * 32) * N + c;
  float v[32];
  #pragma unroll
  for (int kk = 0; kk < 32; ++kk) v[kk] = s[(size_t)kk * N];
  char* d = (char*)dst + (size_t)w * 4096 + j * 16;
  #pragma unroll
  for (int q = 0; q < 4; ++q) {
    int o = q * 8;
    uint4 tv;
    tv.x = f2bf2(v[o + 0], v[o + 1]);
    tv.y = f2bf2(v[o + 2], v[o + 3]);
    tv.z = f2bf2(v[o + 4], v[o + 5]);
    tv.w = f2bf2(v[o + 6], v[o + 7]);
    *(uint4*)(d + q * 1024) = tv;
  }
}

// ===== 256x256 8-phase GEMM core: split staging, reg-pipelined frags =======
// Pair s (phases 2s,2s+1) computes unit I4+s (slot s&3), stages unit I4+3+s
// into slot (s+3)&3 (A: 2 gl16 in even, B: 2 gl16 in odd). Even phase ends
// with vmcnt(6) (before the barrier): guarantees unit s+1 fully landed for
// the odd phase's early frag reads; 3 pairs (~6 phases) of landing slack.
// B frag reads use octet-major layout: conflict-free.

#define G8_PRE()                                                              \
  const int tid = threadIdx.x, lane = tid & 63, wave = tid >> 6;              \
  const int wm = wave >> 2, wn = wave & 3;                                    \
  const int f = lane & 15, g = lane >> 4;                                     \
  const int wud = wave >> 2, wlo = wave & 3;                                  \
  const int row_in = wlo * 16 + (lane >> 2);                                  \
  const int szr = (row_in & 3) ^ ((row_in >> 2) & 3);                         \
  const int qs = (((lane & 3) ^ szr) << 4);                                   \
  const int btile_off = wlo * 1024 + lane * 16;                               \
  const int wv1k = wave * 1024;                                               \
  const int awb = wm * 8192;                                                  \
  int aoff[4], boff[4];                                                       \
  _Pragma("unroll")                                                           \
  for (int ii = 0; ii < 4; ++ii) {                                            \
    int u16 = ii * 16 + f;                                                    \
    aoff[ii] = u16 * 64 + ((g ^ ((u16 & 3) ^ ((u16 >> 2) & 3))) << 4);        \
    boff[ii] = 16384 + wn * 4096 + g * 1024 + u16 * 16;                       \
  }                                                                           \
  f32x4 acc[8][4];                                                            \
  const f32x4 zz = {0.f, 0.f, 0.f, 0.f};                                      \
  _Pragma("unroll")                                                           \
  for (int mi = 0; mi < 8; ++mi)                                              \
    _Pragma("unroll")                                                         \
    for (int ni = 0; ni < 4; ++ni) acc[mi][ni] = zz;

#define G8_EVEN(s, AFC, AFN, BVC, UMAXv)                                      \
  {                                                                           \
    BARX();                                                                   \
    int u_ = I4 + 3 + (s); if (u_ >= (UMAXv)) u_ = (UMAXv) - 1;               \
    char* td_ = lds + ((((s) + 3) & 3) * 32768);                              \
    gl16(pA0 + u_ * 64, td_ + wv1k);                                          \
    gl16(pA1 + u_ * 64, td_ + 8192 + wv1k);                                   \
    const char* cb_ = lds + (((s) & 3) * 32768);                              \
    _Pragma("unroll")                                                         \
    for (int mi = 0; mi < 4; ++mi)                                            \
      AFN[mi] = *(const bf16x8*)(cb_ + awb + 4096 + aoff[mi]);                \
    __builtin_amdgcn_s_setprio(1);                                            \
    _Pragma("unroll")                                                         \
    for (int ni = 0; ni < 4; ++ni)                                            \
      _Pragma("unroll")                                                       \
      for (int mi = 0; mi < 4; ++mi)                                          \
        acc[mi][ni] = __builtin_amdgcn_mfma_f32_16x16x32_bf16(                \
            AFC[mi], BVC[ni], acc[mi][ni], 0, 0, 0);                          \
    __builtin_amdgcn_s_setprio(0);                                            \
    asm volatile("s_waitcnt vmcnt(6)" ::: "memory");                          \
  }

#define G8_ODD(s, AFC, BVC, AFN, BVN, UMAXv)                                  \
  {                                                                           \
    BARX();                                                                   \
    int u_ = I4 + 3 + (s); if (u_ >= (UMAXv)) u_ = (UMAXv) - 1;               \
    char* td_ = lds + ((((s) + 3) & 3) * 32768);                              \
    gl16(pB0 + (size_t)u_ * 4096, td_ + 16384 + wv1k);                        \
    gl16(pB1 + (size_t)u_ * 4096, td_ + 24576 + wv1k);                        \
    const char* nb_ = lds + ((((s) + 1) & 3) * 32768);                        \
    _Pragma("unroll")                                                         \
    for (int mi = 0; mi < 4; ++mi)                                            \
      AFN[mi] = *(const bf16x8*)(nb_ + awb + aoff[mi]);                       \
    _Pragma("unroll")                                                         \
    for (int ni = 0; ni < 4; ++ni)                                            \
      BVN[ni] = *(const bf16x8*)(nb_ + boff[ni]);                             \
    __builtin_amdgcn_s_setprio(1);                                            \
    _Pragma("unroll")                                                         \
    for (int ni = 0; ni < 4; ++ni)                                            \
      _Pragma("unroll")                                                       \
      for (int mi = 0; mi < 4; ++mi)                                          \
        acc[4 + mi][ni] = __builtin_amdgcn_mfma_f32_16x16x32_bf16(            \
            AFC[mi], BVC[ni], acc[4 + mi][ni], 0, 0, 0);                      \
    __builtin_amdgcn_s_setprio(0);                                            \
  }

#define G8_BODY(UMAXv)                                                        \
  _Pragma("unroll")                                                           \
  for (int uu = 0; uu < 3; ++uu) {                                            \
    gl16(pA0 + uu * 64, lds + uu * 32768 + wv1k);                             \
    gl16(pA1 + uu * 64, lds + uu * 32768 + 8192 + wv1k);                      \
    gl16(pB0 + (size_t)uu * 4096, lds + uu * 32768 + 16384 + wv1k);           \
    gl16(pB1 + (size_t)uu * 4096, lds + uu * 32768 + 24576 + wv1k);           \
  }                                                                           \
  asm volatile("s_waitcnt vmcnt(8)" ::: "memory");                            \
  BARX();                                                                     \
  bf16x8 af0[4], af1[4], bv0[4], bv1[4];                                      \
  _Pragma("unroll")                                                           \
  for (int mi = 0; mi < 4; ++mi)                                              \
    af0[mi] = *(const bf16x8*)(lds + awb + aoff[mi]);                         \
  _Pragma("unroll")                                                           \
  for (int ni = 0; ni < 4; ++ni)                                              \
    bv0[ni] = *(const bf16x8*)(lds + boff[ni]);                               \
  for (int I = 0; I < (UMAXv) / 4; ++I) {                                     \
    const int I4 = I * 4;                                                     \
    G8_EVEN(0, af0, af1, bv0, UMAXv); G8_ODD(0, af1, bv0, af0, bv1, UMAXv);   \
    G8_EVEN(1, af0, af1, bv1, UMAXv); G8_ODD(1, af1, bv1, af0, bv0, UMAXv);   \
    G8_EVEN(2, af0, af1, bv0, UMAXv); G8_ODD(2, af1, bv0, af0, bv1, UMAXv);   \
    G8_EVEN(3, af0, af1, bv1, UMAXv); G8_ODD(3, af1, bv1, af0, bv0, UMAXv);   \
  }

// XCD-chunked flat swizzle: consecutive work-ids land on the same XCD.
#define XCD_SWZ(GXv)                                                          \
  const int nb_ = gridDim.x;                                                  \
  const int b_ = blockIdx.x;                                                  \
  const int w_ = (b_ & 7) * (nb_ >> 3) + (b_ >> 3);                           \
  const int bx = w_ % (GXv);                                                  \
  const int by = w_ / (GXv);

// --------------------------------------------------------- shared GEMM1 ----
__global__ __launch_bounds__(512, 2) void s1_kernel(
    const unsigned short* __restrict__ xb, const unsigned short* __restrict__ w13,
    const float* __restrict__ sb1, const float* __restrict__ sb3,
    unsigned short* __restrict__ Hs) {
  __shared__ char lds[131072];
  XCD_SWZ(8);
  const int m0 = by * 256;
  G8_PRE();
  const char* pA0 = (const char*)xb + (size_t)(m0 + wud * 64 + row_in) * 2048 + qs;
  const char* pA1 = pA0 + (size_t)128 * 2048;
  const char* pB0 = (const char*)w13 + ((size_t)(bx * 4 + wud) * 32) * 4096 + btile_off;
  const char* pB1 = (const char*)w13 + ((size_t)(bx * 4 + 2 + wud) * 32) * 4096 + btile_off;
  G8_BODY(32);
  const int colb = bx * 128;
  #pragma unroll
  for (int p2 = 0; p2 < 2; ++p2) {
    int c = colb + wn * 32 + p2 * 16 + f;
    float bb1 = sb1[c], bb3 = sb3[c];
    #pragma unroll
    for (int m8 = 0; m8 < 8; ++m8) {
      int row = m0 + wm * 128 + (m8 >> 2) * 64 + (m8 & 3) * 16 + g * 4;
      #pragma unroll
      for (int r = 0; r < 4; ++r) {
        float v1 = acc[m8][2 * p2][r] + bb1;
        float v3 = acc[m8][2 * p2 + 1][r] + bb3;
        float h = (v1 / (1.f + __expf(-v1))) * v3;
        Hs[(size_t)(row + r) * 1024 + c] = f2bf(h);
      }
    }
  }
}

// --------------------------------------------------------- shared GEMM2 ----
__global__ __launch_bounds__(512, 2) void s2_kernel(
    const unsigned short* __restrict__ Hs, const unsigned short* __restrict__ b2i,
    const float* __restrict__ sb2, float* __restrict__ out) {
  __shared__ char lds[131072];
  XCD_SWZ(4);
  const int m0 = by * 256;
  G8_PRE();
  const char* pA0 = (const char*)Hs + (size_t)(m0 + wud * 64 + row_in) * 2048 + qs;
  const char* pA1 = pA0 + (size_t)128 * 2048;
  const char* pB0 = (const char*)b2i + ((size_t)(bx * 4 + wud) * 32) * 4096 + btile_off;
  const char* pB1 = (const char*)b2i + ((size_t)(bx * 4 + 2 + wud) * 32) * 4096 + btile_off;
  G8_BODY(32);
  #pragma unroll
  for (int ni = 0; ni < 4; ++ni) {
    int c = bx * 256 + wn * 64 + ni * 16 + f;
    float bb = sb2[c];
    #pragma unroll
    for (int m8 = 0; m8 < 8; ++m8) {
      int row = m0 + wm * 128 + (m8 >> 2) * 64 + (m8 & 3) * 16 + g * 4;
      #pragma unroll
      for (int r = 0; r < 4; ++r)
        out[(size_t)(row + r) * 1024 + c] = acc[m8][ni][r] + bb;
    }
  }
}

// --------------------------------------------------------- routed GEMM1 ----
__global__ __launch_bounds__(512, 2) void g1_kernel(
    const unsigned short* __restrict__ xb, const unsigned short* __restrict__ w13,
    const float* __restrict__ b1, const float* __restrict__ b3,
    const int* __restrict__ tok, const int* __restrict__ meta,
    unsigned short* __restrict__ H) {
  __shared__ char lds[131072];
  XCD_SWZ(4);
  if (by >= meta[97]) return;
  const int e = meta[128 + by], m0 = meta[1184 + by];
  const int off_e = meta[64 + e], nrem = meta[e] - m0;
  G8_PRE();
  const int r0a = wud * 64 + row_in;
  const int ix0 = off_e + m0 + ((r0a < nrem) ? r0a : 0);
  const int ix1 = off_e + m0 + ((r0a + 128 < nrem) ? r0a + 128 : 0);
  const char* pA0 = (const char*)xb + (size_t)tok[ix0] * 2048 + qs;
  const char* pA1 = (const char*)xb + (size_t)tok[ix1] * 2048 + qs;
  const char* pB0 = (const char*)w13 + ((size_t)(e * 16 + bx * 4 + wud) * 32) * 4096 + btile_off;
  const char* pB1 = (const char*)w13 + ((size_t)(e * 16 + bx * 4 + 2 + wud) * 32) * 4096 + btile_off;
  G8_BODY(32);
  const int colb = bx * 128;
  #pragma unroll
  for (int p2 = 0; p2 < 2; ++p2) {
    int c = colb + wn * 32 + p2 * 16 + f;
    float bb1 = b1[e * 512 + c], bb3 = b3[e * 512 + c];
    #pragma unroll
    for (int m8 = 0; m8 < 8; ++m8) {
      int row = wm * 128 + (m8 >> 2) * 64 + (m8 & 3) * 16 + g * 4;
      #pragma unroll
      for (int r = 0; r < 4; ++r) {
        if (row + r < nrem) {
          float v1 = acc[m8][2 * p2][r] + bb1;
          float v3 = acc[m8][2 * p2 + 1][r] + bb3;
          float h = (v1 / (1.f + __expf(-v1))) * v3;
          H[(size_t)(off_e + m0 + row + r) * 512 + c] = f2bf(h);
        }
      }
    }
  }
}

// --------------------------------------------------------- routed GEMM2 ----
__global__ __launch_bounds__(512, 2) void g2_kernel(
    const unsigned short* __restrict__ H, const unsigned short* __restrict__ w2i,
    const float* __restrict__ b2, const int* __restrict__ meta,
    unsigned short* __restrict__ Y, int cbase) {
  __shared__ char lds[131072];
  XCD_SWZ(2);
  if (by >= meta[97]) return;
  const int e = meta[128 + by], m0 = meta[1184 + by];
  const int off_e = meta[64 + e], nrem = meta[e] - m0;
  G8_PRE();
  const int r0a = wud * 64 + row_in;
  const int ix0 = off_e + m0 + ((r0a < nrem) ? r0a : 0);
  const int ix1 = off_e + m0 + ((r0a + 128 < nrem) ? r0a + 128 : 0);
  const char* pA0 = (const char*)H + (size_t)ix0 * 1024 + qs;
  const char* pA1 = (const char*)H + (size_t)ix1 * 1024 + qs;
  const int nt0 = (cbase >> 6) + bx * 4;
  const char* pB0 = (const char*)w2i + ((size_t)(e * 16 + nt0 + wud) * 16) * 4096 + btile_off;
  const char* pB1 = (const char*)w2i + ((size_t)(e * 16 + nt0 + 2 + wud) * 16) * 4096 + btile_off;
  G8_BODY(16);
  #pragma unroll
  for (int ni = 0; ni < 4; ++ni) {
    int ycol = bx * 256 + wn * 64 + ni * 16 + f;
    float bb = b2[e * 1024 + cbase + ycol];
    #pragma unroll
    for (int m8 = 0; m8 < 8; ++m8) {
      int row = wm * 128 + (m8 >> 2) * 64 + (m8 & 3) * 16 + g * 4;
      #pragma unroll
      for (int r = 0; r < 4; ++r) {
        if (row + r < nrem)
          Y[(size_t)(off_e + m0 + row + r) * 512 + ycol] = f2bf(acc[m8][ni][r] + bb);
      }
    }
  }
}

// ------------------------------------------------------------- combine ----
__global__ __launch_bounds__(256) void combine_kernel(
    const unsigned short* __restrict__ Y, const int* __restrict__ inv,
    const float* __restrict__ wts, float* __restrict__ out, int cbase) {
  int t = blockIdx.x * 2 + (threadIdx.x >> 7);
  int c = (threadIdx.x & 127) * 4;
  int4 iv = *(const int4*)(inv + t * 4);
  float4 wv = *(const float4*)(wts + t * 4);
  float* op = out + (size_t)t * 1024 + cbase + c;
  float4 o = *(float4*)op;
  uint2 u;
  u = *(const uint2*)(Y + (size_t)iv.x * 512 + c);
  o.x += wv.x * bflo(u.x); o.y += wv.x * bfhi(u.x);
  o.z += wv.x * bflo(u.y); o.w += wv.x * bfhi(u.y);
  u = *(const uint2*)(Y + (size_t)iv.y * 512 + c);
  o.x += wv.y * bflo(u.x); o.y += wv.y * bfhi(u.x);
  o.z += wv.y * bflo(u.y); o.w += wv.y * bfhi(u.y);
  u = *(const uint2*)(Y + (size_t)iv.z * 512 + c);
  o.x += wv.z * bflo(u.x); o.y += wv.z * bfhi(u.x);
  o.z += wv.z * bflo(u.y); o.w += wv.z * bfhi(u.y);
  u = *(const uint2*)(Y + (size_t)iv.w * 512 + c);
  o.x += wv.w * bflo(u.x); o.y += wv.w * bfhi(u.x);
  o.z += wv.w * bflo(u.y); o.w += wv.w * bfhi(u.y);
  *(float4*)op = o;
}

// ------------------------------------------------------------------ host ----
extern "C" void kernel_launch(void* const* d_in, const int* in_sizes, int n_in,
                              void* d_out, int out_size, void* d_ws, size_t ws_size,
                              hipStream_t stream) {
  const float* x   = (const float*)d_in[0];
  const float* gw  = (const float*)d_in[1];
  const float* gb  = (const float*)d_in[2];
  const float* w1  = (const float*)d_in[3];
  const float* b1  = (const float*)d_in[4];
  const float* w3  = (const float*)d_in[5];
  const float* b3  = (const float*)d_in[6];
  const float* w2  = (const float*)d_in[7];
  const float* b2  = (const float*)d_in[8];
  const float* sw1 = (const float*)d_in[9];
  const float* sb1 = (const float*)d_in[10];
  const float* sw3 = (const float*)d_in[11];
  const float* sb3 = (const float*)d_in[12];
  const float* sw2 = (const float*)d_in[13];
  const float* sb2 = (const float*)d_in[14];
  float* out = (float*)d_out;
  char* ws = (char*)d_ws;

  const size_t OFF_XB   = 134217728;
  const size_t OFF_W13I = 201326592;
  const size_t OFF_W2I  = 268435456;
  const size_t OFF_S13I = 301989888;
  const size_t OFF_SW2I = 306184192;
  const size_t OFF_IDX  = 308281344;
  const size_t OFF_WTS  = 308805632;
  const size_t OFF_TOK  = 309329920;
  const size_t OFF_INV  = 309854208;
  const size_t OFF_META = 310378496;
  if (ws_size < OFF_META + 8960) return;

  unsigned short* H    = (unsigned short*)ws;
  unsigned short* xb   = (unsigned short*)(ws + OFF_XB);
  unsigned short* Yb   = (unsigned short*)(ws + OFF_XB);
  unsigned short* w13i = (unsigned short*)(ws + OFF_W13I);
  unsigned short* w2i  = (unsigned short*)(ws + OFF_W2I);
  unsigned short* s13i = (unsigned short*)(ws + OFF_S13I);
  unsigned short* sw2i = (unsigned short*)(ws + OFF_SW2I);
  int*   idx  = (int*)(ws + OFF_IDX);
  float* wts  = (float*)(ws + OFF_WTS);
  int*   tokl = (int*)(ws + OFF_TOK);
  int*   inv  = (int*)(ws + OFF_INV);
  int*   meta = (int*)(ws + OFF_META);

  hipMemsetAsync(meta, 0, 128, stream);
  gate_kernel<<<dim3(8192), dim3(256), 0, stream>>>(x, gw, gb, idx, wts, xb);
  count_kernel<<<dim3(512), dim3(256), 0, stream>>>(idx, meta);
  scan_kernel<<<dim3(1), dim3(64), 0, stream>>>(meta);
  scatter_kernel<<<dim3(512), dim3(256), 0, stream>>>(idx, meta, tokl, inv);
  repack13_kernel<<<dim3(4096), dim3(256), 0, stream>>>(w1, w3, w13i, 1024, 512, 16);
  repack_kernel<<<dim3(2048), dim3(256), 0, stream>>>(w2, w2i, 512, 1024, 256);
  repack13_kernel<<<dim3(256), dim3(256), 0, stream>>>(sw1, sw3, s13i, 1024, 1024, 32);
  repack_kernel<<<dim3(128), dim3(256), 0, stream>>>(sw2, sw2i, 1024, 1024, 512);
  s1_kernel<<<dim3(1024), dim3(512), 0, stream>>>(xb, s13i, sb1, sb3, H);
  s2_kernel<<<dim3(512), dim3(512), 0, stream>>>(H, sw2i, sb2, out);
  g1_kernel<<<dim3(2176), dim3(512), 0, stream>>>(xb, w13i, b1, b3, tokl, meta, H);
  g2_kernel<<<dim3(1088), dim3(512), 0, stream>>>(H, w2i, b2, meta, Yb, 0);
  combine_kernel<<<dim3(16384), dim3(256), 0, stream>>>(Yb, inv, wts, out, 0);
  g2_kernel<<<dim3(1088), dim3(512), 0, stream>>>(H, w2i, b2, meta, Yb, 512);
  combine_kernel<<<dim3(16384), dim3(256), 0, stream>>>(Yb, inv, wts, out, 512);
}

// Round 11
// 1396.943 us; speedup vs baseline: 1.2366x; 1.0690x over previous
//
#include <hip/hip_runtime.h>
#include <stdint.h>

#define DIM_    1024
#define INTER_  512

typedef short bf16x4 __attribute__((ext_vector_type(4)));
typedef short bf16x8 __attribute__((ext_vector_type(8)));
typedef float f32x4  __attribute__((ext_vector_type(4)));

__device__ __forceinline__ unsigned short f2bf(float f) {
  union { float f; unsigned u; } v; v.f = f;
  return (unsigned short)((v.u + 0x7FFFu + ((v.u >> 16) & 1u)) >> 16);
}
__device__ __forceinline__ unsigned f2bf2(float a, float b) {
  union { float f; unsigned u; } va, vb; va.f = a; vb.f = b;
  unsigned ra = (va.u + 0x7FFFu + ((va.u >> 16) & 1u)) >> 16;
  unsigned rb = (vb.u + 0x7FFFu + ((vb.u >> 16) & 1u)) >> 16;
  return ra | (rb << 16);
}
__device__ __forceinline__ float bfhi(unsigned u) {
  union { unsigned u; float f; } v; v.u = u & 0xffff0000u; return v.f;
}
__device__ __forceinline__ float bflo(unsigned u) {
  union { unsigned u; float f; } v; v.u = u << 16; return v.f;
}

__device__ __forceinline__ void gl16(const void* g, void* l) {
  __builtin_amdgcn_global_load_lds(
      (const __attribute__((address_space(1))) unsigned int*)g,
      (__attribute__((address_space(3))) unsigned int*)l, 16, 0, 0);
}

#define BARX() do { asm volatile("" ::: "memory"); \
                    __builtin_amdgcn_s_barrier();  \
                    asm volatile("" ::: "memory"); } while (0)

// ---------------------------------------------------------------- gate ----
__global__ __launch_bounds__(256) void gate_kernel(
    const float* __restrict__ x, const float* __restrict__ gw,
    const float* __restrict__ gb, int* __restrict__ idx, float* __restrict__ wts,
    unsigned short* __restrict__ xb) {
  __shared__ double s_sc[4][32];
  __shared__ double s_gs[4][8];
  const int wid = threadIdx.x >> 6, lane = threadIdx.x & 63;
  const int t = blockIdx.x * 4 + wid;
  {
    const float* xrow = x + (size_t)t * DIM_ + lane * 16;
    unsigned short* xbrow = xb + (size_t)t * DIM_ + lane * 16;
    float4 f0 = *(const float4*)(xrow);
    float4 f1 = *(const float4*)(xrow + 4);
    float4 f2v = *(const float4*)(xrow + 8);
    float4 f3v = *(const float4*)(xrow + 12);
    uint4 o0, o1;
    o0.x = f2bf2(f0.x, f0.y);  o0.y = f2bf2(f0.z, f0.w);
    o0.z = f2bf2(f1.x, f1.y);  o0.w = f2bf2(f1.z, f1.w);
    o1.x = f2bf2(f2v.x, f2v.y); o1.y = f2bf2(f2v.z, f2v.w);
    o1.z = f2bf2(f3v.x, f3v.y); o1.w = f2bf2(f3v.z, f3v.w);
    *(uint4*)(xbrow) = o0;
    *(uint4*)(xbrow + 8) = o1;
  }
  const int e = lane & 31, half = lane >> 5;
  const float* xr  = x  + (size_t)t * DIM_ + half * 512;
  const float* gwp = gw + (size_t)half * 512 * 32 + e;
  double a0 = 0, a1 = 0, a2 = 0, a3 = 0;
  for (int k = 0; k < 512; k += 4) {
    float4 xv = *(const float4*)(xr + k);
    a0 += (double)xv.x * (double)gwp[(k + 0) * 32];
    a1 += (double)xv.y * (double)gwp[(k + 1) * 32];
    a2 += (double)xv.z * (double)gwp[(k + 2) * 32];
    a3 += (double)xv.w * (double)gwp[(k + 3) * 32];
  }
  double lg = (a0 + a1) + (a2 + a3);
  lg += __shfl_xor(lg, 32);
  lg += (double)gb[e];
  double m = lg;
  #pragma unroll
  for (int d = 1; d < 32; d <<= 1) m = fmax(m, __shfl_xor(m, d));
  double ex = exp(lg - m);
  double ssum = ex;
  #pragma unroll
  for (int d = 1; d < 32; d <<= 1) ssum += __shfl_xor(ssum, d);
  double sc = ex / ssum;
  double p  = __shfl_xor(sc, 1);
  double m1 = fmax(sc, p), n1 = fmin(sc, p);
  double m2 = __shfl_xor(m1, 2), n2 = __shfl_xor(n1, 2);
  double gs = (m1 >= m2) ? (m1 + fmax(n1, m2)) : (m2 + fmax(n2, m1));
  if (lane < 32) {
    s_sc[wid][e] = sc;
    if ((e & 3) == 0) s_gs[wid][e >> 2] = gs;
  }
  __syncthreads();
  if (lane == 0) {
    unsigned kmask = 0;
    for (int it = 0; it < 4; ++it) {
      int bg = 0; double bv = -1.0;
      for (int g = 0; g < 8; ++g)
        if (!((kmask >> g) & 1u) && s_gs[wid][g] > bv) { bv = s_gs[wid][g]; bg = g; }
      kmask |= 1u << bg;
    }
    unsigned umask = 0;
    for (int slot = 0; slot < 4; ++slot) {
      int be = 0; double bv = -1.0;
      for (int ee = 0; ee < 32; ++ee)
        if (((kmask >> (ee >> 2)) & 1u) && !((umask >> ee) & 1u) && s_sc[wid][ee] > bv) {
          bv = s_sc[wid][ee]; be = ee;
        }
      umask |= 1u << be;
      idx[t * 4 + slot] = be;
      wts[t * 4 + slot] = (float)bv;
    }
  }
}

// ------------------------------------------------- dispatch bookkeeping ----
__global__ __launch_bounds__(256) void count_kernel(const int* __restrict__ idx,
                                                    int* __restrict__ meta) {
  __shared__ int h[32];
  int tid = threadIdx.x;
  if (tid < 32) h[tid] = 0;
  __syncthreads();
  atomicAdd(&h[idx[blockIdx.x * 256 + tid]], 1);
  __syncthreads();
  if (tid < 32 && h[tid]) atomicAdd(&meta[tid], h[tid]);
}

__global__ void scan_kernel(int* __restrict__ meta) {
  int lane = threadIdx.x & 63;
  if (lane < 32) {
    int c = meta[lane];
    int pre = c;
    #pragma unroll
    for (int d = 1; d < 32; d <<= 1) { int t = __shfl_up(pre, d); if (lane >= d) pre += t; }
    int excl = pre - c;
    meta[64 + lane] = excl;
    meta[32 + lane] = excl;
    int nt = (c + 255) >> 8;
    int ntp = nt;
    #pragma unroll
    for (int d = 1; d < 32; d <<= 1) { int t = __shfl_up(ntp, d); if (lane >= d) ntp += t; }
    int ntExcl = ntp - nt;
    for (int k = 0; k < nt; ++k) { meta[128 + ntExcl + k] = lane; meta[1184 + ntExcl + k] = k << 8; }
    if (lane == 31) { meta[96] = excl + c; meta[97] = ntExcl + nt; }
  }
}

__global__ __launch_bounds__(256) void scatter_kernel(
    const int* __restrict__ idx, int* __restrict__ meta,
    int* __restrict__ tok, int* __restrict__ inv) {
  int i = blockIdx.x * 256 + threadIdx.x;
  int lane = threadIdx.x & 63;
  int e = idx[i];
  unsigned long long m = ~0ull;
  #pragma unroll
  for (int b = 0; b < 5; ++b) {
    unsigned long long vote = __ballot((e >> b) & 1);
    m &= ((e >> b) & 1) ? vote : ~vote;
  }
  int leader = __ffsll((long long)m) - 1;
  int rank = __popcll(m & ((1ull << lane) - 1));
  int base = 0;
  if (lane == leader) base = atomicAdd(&meta[32 + e], (int)__popcll(m));
  base = __shfl(base, leader);
  int p = base + rank;
  tok[p] = i >> 2;
  inv[i] = p;
}

// ----------------------------------------------------------- repacking ----
// B-image tiles OCTET-MAJOR (conflict-free reads): tile 4KB, k-octet q of
// col j at q*1024 + j*16.
__global__ __launch_bounds__(256) void repack_kernel(
    const float* __restrict__ src, unsigned short* __restrict__ dst,
    int K, int N, int tilesPerMat) {
  const int w = blockIdx.x * 4 + (threadIdx.x >> 6);
  const int j = threadIdx.x & 63;
  const int e = w / tilesPerMat, rem = w % tilesPerMat;
  const int kSteps = K >> 5;
  const int nt = rem / kSteps, kq = rem % kSteps;
  const float* s = src + (size_t)e * K * N + (size_t)(kq * 32) * N + nt * 64 + j;
  float v[32];
  #pragma unroll
  for (int kk = 0; kk < 32; ++kk) v[kk] = s[(size_t)kk * N];
  char* d = (char*)dst + (size_t)w * 4096 + j * 16;
  #pragma unroll
  for (int q = 0; q < 4; ++q) {
    int o = q * 8;
    uint4 tv;
    tv.x = f2bf2(v[o + 0], v[o + 1]);
    tv.y = f2bf2(v[o + 2], v[o + 3]);
    tv.z = f2bf2(v[o + 4], v[o + 5]);
    tv.w = f2bf2(v[o + 6], v[o + 7]);
    *(uint4*)(d + q * 1024) = tv;
  }
}

__global__ __launch_bounds__(256) void repack13_kernel(
    const float* __restrict__ src1, const float* __restrict__ src3,
    unsigned short* __restrict__ dst, int K, int N, int jtTiles) {
  const int w = blockIdx.x * 4 + (threadIdx.x >> 6);
  const int j = threadIdx.x & 63;
  const int kSteps = K >> 5;
  const int tpm = jtTiles * kSteps;
  const int e = w / tpm, rem = w % tpm;
  const int jt = rem / kSteps, kq = rem % kSteps;
  const int jg = jt * 64 + j;
  const int c = ((jg >> 5) << 4) + (jg & 15);
  const float* s = (((jg >> 4) & 1) ? src3 : src1)
                 + (size_t)e * K * N + (size_t)(kq * 32) * N + c;
  float v[32];
  #pragma unroll
  for (int kk = 0; kk < 32; ++kk) v[kk] = s[(size_t)kk * N];
  char* d = (char*)dst + (size_t)w * 4096 + j * 16;
  #pragma unroll
  for (int q = 0; q < 4; ++q) {
    int o = q * 8;
    uint4 tv;
    tv.x = f2bf2(v[o + 0], v[o + 1]);
    tv.y = f2bf2(v[o + 2], v[o + 3]);
    tv.z = f2bf2(v[o + 4], v[o + 5]);
    tv.w = f2bf2(v[o + 6], v[o + 7]);
    *(uint4*)(d + q * 1024) = tv;
  }
}

// ====== 256x128 GEMM core, 3-slot LDS ring (24KB/slot), 2 blocks/CU ========
// 8 waves = 4m x 2n, per-wave C = 64x64 (acc[4][4], 64 AGPR). One phase per
// 32k unit: {8 ds_read + 3 gl16 -> barrier -> 16 MFMA -> vmcnt(3) -> barrier}.
// Slot: A rows 0-127 at [0,8K) (row*64, 16B slots 2-way swizzled), rows
// 128-255 at [8K,16K); B at [16K,24K) = 2 x 4KB octet-major tiles.

#define G4_PRE()                                                              \
  const int tid = threadIdx.x, lane = tid & 63, wave = tid >> 6;              \
  const int wm = wave >> 1, wn = wave & 1;                                    \
  const int f = lane & 15, g = lane >> 4;                                     \
  const int rsg = wave * 16 + (lane >> 2);                                    \
  const int qs = (((lane & 3) ^ ((rsg & 3) ^ ((rsg >> 2) & 3))) << 4);        \
  const int wv1k = wave * 1024;                                               \
  const int bso = (wave & 3) * 1024 + lane * 16;                              \
  int aoff[4], boff[4];                                                       \
  _Pragma("unroll")                                                           \
  for (int ii = 0; ii < 4; ++ii) {                                            \
    int u16 = ii * 16 + f;                                                    \
    aoff[ii] = (wm >> 1) * 8192 + (wm & 1) * 4096 + u16 * 64 +                \
               ((g ^ ((u16 & 3) ^ ((u16 >> 2) & 3))) << 4);                   \
    boff[ii] = 16384 + wn * 4096 + g * 1024 + u16 * 16;                       \
  }                                                                           \
  f32x4 acc[4][4];                                                            \
  const f32x4 zz = {0.f, 0.f, 0.f, 0.f};                                      \
  _Pragma("unroll")                                                           \
  for (int mi = 0; mi < 4; ++mi)                                              \
    _Pragma("unroll")                                                         \
    for (int ni = 0; ni < 4; ++ni) acc[mi][ni] = zz;

#define G4_STAGE(td, u_)                                                      \
  gl16(pA0 + (u_) * 64, (td) + wv1k);                                         \
  gl16(pA1 + (u_) * 64, (td) + 8192 + wv1k);                                  \
  gl16(pB + (size_t)(u_) * 4096, (td) + 16384 + wv1k);

#define G4_BODY(NU)                                                           \
  {                                                                           \
    G4_STAGE(lds, 0);                                                         \
    G4_STAGE(lds + 24576, ((NU) > 1 ? 1 : 0));                                \
    asm volatile("s_waitcnt vmcnt(3)" ::: "memory");                          \
    BARX();                                                                   \
  }                                                                           \
  int bc = 0, bt = 49152;                                                     \
  for (int u = 0; u < (NU); ++u) {                                            \
    const char* cb = lds + bc;                                                \
    bf16x8 af[4], bv[4];                                                      \
    _Pragma("unroll")                                                         \
    for (int mi = 0; mi < 4; ++mi) af[mi] = *(const bf16x8*)(cb + aoff[mi]);  \
    _Pragma("unroll")                                                         \
    for (int ni = 0; ni < 4; ++ni) bv[ni] = *(const bf16x8*)(cb + boff[ni]);  \
    int u_ = u + 2; if (u_ > (NU) - 1) u_ = (NU) - 1;                         \
    char* td = lds + bt;                                                      \
    G4_STAGE(td, u_);                                                         \
    BARX();                                                                   \
    __builtin_amdgcn_s_setprio(1);                                            \
    _Pragma("unroll")                                                         \
    for (int ni = 0; ni < 4; ++ni)                                            \
      _Pragma("unroll")                                                       \
      for (int mi = 0; mi < 4; ++mi)                                          \
        acc[mi][ni] = __builtin_amdgcn_mfma_f32_16x16x32_bf16(                \
            af[mi], bv[ni], acc[mi][ni], 0, 0, 0);                            \
    __builtin_amdgcn_s_setprio(0);                                            \
    asm volatile("s_waitcnt vmcnt(3)" ::: "memory");                          \
    BARX();                                                                   \
    bc = (bc == 49152) ? 0 : bc + 24576;                                      \
    bt = (bt == 49152) ? 0 : bt + 24576;                                      \
  }

// XCD-chunked flat swizzle: consecutive work-ids land on the same XCD.
#define XCD_SWZ(GXv)                                                          \
  const int nb_ = gridDim.x;                                                  \
  const int b_ = blockIdx.x;                                                  \
  const int w_ = (b_ & 7) * (nb_ >> 3) + (b_ >> 3);                           \
  const int bx = w_ % (GXv);                                                  \
  const int by = w_ / (GXv);

// --------------------------------------------------------- shared GEMM1 ----
__global__ __launch_bounds__(512, 4) void s1_kernel(
    const unsigned short* __restrict__ xb, const unsigned short* __restrict__ w13,
    const float* __restrict__ sb1, const float* __restrict__ sb3,
    unsigned short* __restrict__ Hs) {
  __shared__ char lds[73728];
  XCD_SWZ(16);
  const int m0 = by * 256;
  G4_PRE();
  const char* pA0 = (const char*)xb + (size_t)(m0 + rsg) * 2048 + qs;
  const char* pA1 = pA0 + (size_t)128 * 2048;
  const char* pB = (const char*)w13 + ((size_t)(bx * 2 + (wave >> 2)) * 32) * 4096 + bso;
  G4_BODY(32);
  const int colb = bx * 64;
  #pragma unroll
  for (int p2 = 0; p2 < 2; ++p2) {
    int c = colb + wn * 32 + p2 * 16 + f;
    float bb1 = sb1[c], bb3 = sb3[c];
    #pragma unroll
    for (int mi = 0; mi < 4; ++mi) {
      int row = m0 + wm * 64 + mi * 16 + g * 4;
      #pragma unroll
      for (int r = 0; r < 4; ++r) {
        float v1 = acc[mi][2 * p2][r] + bb1;
        float v3 = acc[mi][2 * p2 + 1][r] + bb3;
        float h = (v1 / (1.f + __expf(-v1))) * v3;
        Hs[(size_t)(row + r) * 1024 + c] = f2bf(h);
      }
    }
  }
}

// --------------------------------------------------------- shared GEMM2 ----
__global__ __launch_bounds__(512, 4) void s2_kernel(
    const unsigned short* __restrict__ Hs, const unsigned short* __restrict__ b2i,
    const float* __restrict__ sb2, float* __restrict__ out) {
  __shared__ char lds[73728];
  XCD_SWZ(8);
  const int m0 = by * 256;
  G4_PRE();
  const char* pA0 = (const char*)Hs + (size_t)(m0 + rsg) * 2048 + qs;
  const char* pA1 = pA0 + (size_t)128 * 2048;
  const char* pB = (const char*)b2i + ((size_t)(bx * 2 + (wave >> 2)) * 32) * 4096 + bso;
  G4_BODY(32);
  #pragma unroll
  for (int ni = 0; ni < 4; ++ni) {
    int c = bx * 128 + wn * 64 + ni * 16 + f;
    float bb = sb2[c];
    #pragma unroll
    for (int mi = 0; mi < 4; ++mi) {
      int row = m0 + wm * 64 + mi * 16 + g * 4;
      #pragma unroll
      for (int r = 0; r < 4; ++r)
        out[(size_t)(row + r) * 1024 + c] = acc[mi][ni][r] + bb;
    }
  }
}

// --------------------------------------------------------- routed GEMM1 ----
__global__ __launch_bounds__(512, 4) void g1_kernel(
    const unsigned short* __restrict__ xb, const unsigned short* __restrict__ w13,
    const float* __restrict__ b1, const float* __restrict__ b3,
    const int* __restrict__ tok, const int* __restrict__ meta,
    unsigned short* __restrict__ H) {
  __shared__ char lds[73728];
  XCD_SWZ(8);
  if (by >= meta[97]) return;
  const int e = meta[128 + by], m0 = meta[1184 + by];
  const int off_e = meta[64 + e], nrem = meta[e] - m0;
  G4_PRE();
  const int ix0 = off_e + m0 + ((rsg < nrem) ? rsg : 0);
  const int ix1 = off_e + m0 + ((rsg + 128 < nrem) ? rsg + 128 : 0);
  const char* pA0 = (const char*)xb + (size_t)tok[ix0] * 2048 + qs;
  const char* pA1 = (const char*)xb + (size_t)tok[ix1] * 2048 + qs;
  const char* pB = (const char*)w13 + ((size_t)(e * 16 + bx * 2 + (wave >> 2)) * 32) * 4096 + bso;
  G4_BODY(32);
  const int colb = bx * 64;
  #pragma unroll
  for (int p2 = 0; p2 < 2; ++p2) {
    int c = colb + wn * 32 + p2 * 16 + f;
    float bb1 = b1[e * 512 + c], bb3 = b3[e * 512 + c];
    #pragma unroll
    for (int mi = 0; mi < 4; ++mi) {
      int row = wm * 64 + mi * 16 + g * 4;
      #pragma unroll
      for (int r = 0; r < 4; ++r) {
        if (row + r < nrem) {
          float v1 = acc[mi][2 * p2][r] + bb1;
          float v3 = acc[mi][2 * p2 + 1][r] + bb3;
          float h = (v1 / (1.f + __expf(-v1))) * v3;
          H[(size_t)(off_e + m0 + row + r) * 512 + c] = f2bf(h);
        }
      }
    }
  }
}

// --------------------------------------------------------- routed GEMM2 ----
__global__ __launch_bounds__(512, 4) void g2_kernel(
    const unsigned short* __restrict__ H, const unsigned short* __restrict__ w2i,
    const float* __restrict__ b2, const int* __restrict__ meta,
    unsigned short* __restrict__ Y, int cbase) {
  __shared__ char lds[73728];
  XCD_SWZ(4);
  if (by >= meta[97]) return;
  const int e = meta[128 + by], m0 = meta[1184 + by];
  const int off_e = meta[64 + e], nrem = meta[e] - m0;
  G4_PRE();
  const int ix0 = off_e + m0 + ((rsg < nrem) ? rsg : 0);
  const int ix1 = off_e + m0 + ((rsg + 128 < nrem) ? rsg + 128 : 0);
  const char* pA0 = (const char*)H + (size_t)ix0 * 1024 + qs;
  const char* pA1 = (const char*)H + (size_t)ix1 * 1024 + qs;
  const int nt0 = (cbase >> 6) + bx * 2;
  const char* pB = (const char*)w2i + ((size_t)(e * 16 + nt0 + (wave >> 2)) * 16) * 4096 + bso;
  G4_BODY(16);
  #pragma unroll
  for (int ni = 0; ni < 4; ++ni) {
    int ycol = bx * 128 + wn * 64 + ni * 16 + f;
    float bb = b2[e * 1024 + cbase + ycol];
    #pragma unroll
    for (int mi = 0; mi < 4; ++mi) {
      int row = wm * 64 + mi * 16 + g * 4;
      #pragma unroll
      for (int r = 0; r < 4; ++r) {
        if (row + r < nrem)
          Y[(size_t)(off_e + m0 + row + r) * 512 + ycol] = f2bf(acc[mi][ni][r] + bb);
      }
    }
  }
}

// ------------------------------------------------------------- combine ----
__global__ __launch_bounds__(256) void combine_kernel(
    const unsigned short* __restrict__ Y, const int* __restrict__ inv,
    const float* __restrict__ wts, float* __restrict__ out, int cbase) {
  int t = blockIdx.x * 2 + (threadIdx.x >> 7);
  int c = (threadIdx.x & 127) * 4;
  int4 iv = *(const int4*)(inv + t * 4);
  float4 wv = *(const float4*)(wts + t * 4);
  float* op = out + (size_t)t * 1024 + cbase + c;
  float4 o = *(float4*)op;
  uint2 u;
  u = *(const uint2*)(Y + (size_t)iv.x * 512 + c);
  o.x += wv.x * bflo(u.x); o.y += wv.x * bfhi(u.x);
  o.z += wv.x * bflo(u.y); o.w += wv.x * bfhi(u.y);
  u = *(const uint2*)(Y + (size_t)iv.y * 512 + c);
  o.x += wv.y * bflo(u.x); o.y += wv.y * bfhi(u.x);
  o.z += wv.y * bflo(u.y); o.w += wv.y * bfhi(u.y);
  u = *(const uint2*)(Y + (size_t)iv.z * 512 + c);
  o.x += wv.z * bflo(u.x); o.y += wv.z * bfhi(u.x);
  o.z += wv.z * bflo(u.y); o.w += wv.z * bfhi(u.y);
  u = *(const uint2*)(Y + (size_t)iv.w * 512 + c);
  o.x += wv.w * bflo(u.x); o.y += wv.w * bfhi(u.x);
  o.z += wv.w * bflo(u.y); o.w += wv.w * bfhi(u.y);
  *(float4*)op = o;
}

// ------------------------------------------------------------------ host ----
extern "C" void kernel_launch(void* const* d_in, const int* in_sizes, int n_in,
                              void* d_out, int out_size, void* d_ws, size_t ws_size,
                              hipStream_t stream) {
  const float* x   = (const float*)d_in[0];
  const float* gw  = (const float*)d_in[1];
  const float* gb  = (const float*)d_in[2];
  const float* w1  = (const float*)d_in[3];
  const float* b1  = (const float*)d_in[4];
  const float* w3  = (const float*)d_in[5];
  const float* b3  = (const float*)d_in[6];
  const float* w2  = (const float*)d_in[7];
  const float* b2  = (const float*)d_in[8];
  const float* sw1 = (const float*)d_in[9];
  const float* sb1 = (const float*)d_in[10];
  const float* sw3 = (const float*)d_in[11];
  const float* sb3 = (const float*)d_in[12];
  const float* sw2 = (const float*)d_in[13];
  const float* sb2 = (const float*)d_in[14];
  float* out = (float*)d_out;
  char* ws = (char*)d_ws;

  const size_t OFF_XB   = 134217728;
  const size_t OFF_W13I = 201326592;
  const size_t OFF_W2I  = 268435456;
  const size_t OFF_S13I = 301989888;
  const size_t OFF_SW2I = 306184192;
  const size_t OFF_IDX  = 308281344;
  const size_t OFF_WTS  = 308805632;
  const size_t OFF_TOK  = 309329920;
  const size_t OFF_INV  = 309854208;
  const size_t OFF_META = 310378496;
  if (ws_size < OFF_META + 8960) return;

  unsigned short* H    = (unsigned short*)ws;
  unsigned short* xb   = (unsigned short*)(ws + OFF_XB);
  unsigned short* Yb   = (unsigned short*)(ws + OFF_XB);
  unsigned short* w13i = (unsigned short*)(ws + OFF_W13I);
  unsigned short* w2i  = (unsigned short*)(ws + OFF_W2I);
  unsigned short* s13i = (unsigned short*)(ws + OFF_S13I);
  unsigned short* sw2i = (unsigned short*)(ws + OFF_SW2I);
  int*   idx  = (int*)(ws + OFF_IDX);
  float* wts  = (float*)(ws + OFF_WTS);
  int*   tokl = (int*)(ws + OFF_TOK);
  int*   inv  = (int*)(ws + OFF_INV);
  int*   meta = (int*)(ws + OFF_META);

  hipMemsetAsync(meta, 0, 128, stream);
  gate_kernel<<<dim3(8192), dim3(256), 0, stream>>>(x, gw, gb, idx, wts, xb);
  count_kernel<<<dim3(512), dim3(256), 0, stream>>>(idx, meta);
  scan_kernel<<<dim3(1), dim3(64), 0, stream>>>(meta);
  scatter_kernel<<<dim3(512), dim3(256), 0, stream>>>(idx, meta, tokl, inv);
  repack13_kernel<<<dim3(4096), dim3(256), 0, stream>>>(w1, w3, w13i, 1024, 512, 16);
  repack_kernel<<<dim3(2048), dim3(256), 0, stream>>>(w2, w2i, 512, 1024, 256);
  repack13_kernel<<<dim3(256), dim3(256), 0, stream>>>(sw1, sw3, s13i, 1024, 1024, 32);
  repack_kernel<<<dim3(128), dim3(256), 0, stream>>>(sw2, sw2i, 1024, 1024, 512);
  s1_kernel<<<dim3(2048), dim3(512), 0, stream>>>(xb, s13i, sb1, sb3, H);
  s2_kernel<<<dim3(1024), dim3(512), 0, stream>>>(H, sw2i, sb2, out);
  g1_kernel<<<dim3(4352), dim3(512), 0, stream>>>(xb, w13i, b1, b3, tokl, meta, H);
  g2_kernel<<<dim3(2176), dim3(512), 0, stream>>>(H, w2i, b2, meta, Yb, 0);
  combine_kernel<<<dim3(16384), dim3(256), 0, stream>>>(Yb, inv, wts, out, 0);
  g2_kernel<<<dim3(2176), dim3(512), 0, stream>>>(H, w2i, b2, meta, Yb, 512);
  combine_kernel<<<dim3(16384), dim3(256), 0, stream>>>(Yb, inv, wts, out, 512);
}